// Round 5
// baseline (546.886 us; speedup 1.0000x reference)
//
#include <hip/hip_runtime.h>
#include <hip/hip_bf16.h>

typedef __hip_bfloat16 bf16;
typedef unsigned short u16;
typedef u16 u16x8 __attribute__((ext_vector_type(8)));
typedef u16 u16x4v __attribute__((ext_vector_type(4)));
typedef short bf16x8 __attribute__((ext_vector_type(8)));
typedef float f32x4 __attribute__((ext_vector_type(4)));

__device__ __forceinline__ float b2f(u16 u) {
    unsigned v = ((unsigned)u) << 16;
    float f; __builtin_memcpy(&f, &v, 4); return f;
}
__device__ __forceinline__ u16 f2u(float f) {
    bf16 h = __float2bfloat16(f);
    u16 u; __builtin_memcpy(&u, &h, 2); return u;
}
__device__ __forceinline__ float sigmoidf_(float x) { return 1.f / (1.f + expf(-x)); }
__device__ __forceinline__ void load8f(const float* __restrict__ p, float* x) {
    float4 a = *reinterpret_cast<const float4*>(p);
    float4 b = *reinterpret_cast<const float4*>(p + 4);
    x[0]=a.x; x[1]=a.y; x[2]=a.z; x[3]=a.w; x[4]=b.x; x[5]=b.y; x[6]=b.z; x[7]=b.w;
}

// async global->LDS, 16B per lane. LDS dest = wave-uniform base + lane*16.
__device__ __forceinline__ void gld16(const void* g, void* l) {
    typedef __attribute__((address_space(1))) const unsigned int GU;
    typedef __attribute__((address_space(3))) unsigned int LU;
    __builtin_amdgcn_global_load_lds((GU*)(unsigned long long)g,
                                     (LU*)(unsigned int)(unsigned long long)l, 16, 0, 0);
}

// ---------------------------------------------------------------------------
// m97-structure MFMA GEMM: C = A[m][k] . Bt[n][k]^T, batched over z.
// 128x128 tile, BK=32, 256 thr (4 waves 2x2), global_load_lds, linear LDS.
// EPI 0: bf16 outb = acc*scale + bias, stride sO per z
// EPI 2: Wo: out1=pd=acc+bias; out2=pa=pd+anchor; outb=bf16(pa)   (z=0)
// EPI 3: v_t: outb[(row>>11)*2048*512 + col*2048 + (row&2047)] = bf16(acc+bias)
// ---------------------------------------------------------------------------
template<int EPI>
__global__ __launch_bounds__(256)
void k_mfma(const bf16* __restrict__ A, long long sA, int lda,
            const bf16* __restrict__ Bt, long long sB, int ldb,
            const float* __restrict__ bias,
            bf16* __restrict__ outb, long long sO,
            float* __restrict__ out1, float* __restrict__ out2,
            const float* __restrict__ anchor,
            int N, int K, float scale)
{
    __shared__ short As[4096];
    __shared__ short Bs[4096];
    const int tid = threadIdx.x;
    const int z = blockIdx.z;
    const int n0 = blockIdx.x * 128, m0 = blockIdx.y * 128;
    const bf16* Az = A + (long long)z * sA;
    const bf16* Bz = Bt + (long long)z * sB;
    const int lrow = tid >> 2;          // 0..63 staging row
    const int lcol = (tid & 3) * 8;     // k-chunk within 32
    const int lane = tid & 63, w = tid >> 6;
    const int wm = (w >> 1) * 64, wn = (w & 1) * 64;
    const int fr = lane & 15, fq = lane >> 4;
    char* AsW = (char*)As + w * 1024;   // wave-uniform LDS staging base
    char* BsW = (char*)Bs + w * 1024;

    f32x4 acc[4][4];
#pragma unroll
    for (int i = 0; i < 4; ++i)
#pragma unroll
        for (int j = 0; j < 4; ++j) acc[i][j] = f32x4{0.f, 0.f, 0.f, 0.f};

    for (int k0 = 0; k0 < K; k0 += 32) {
        const bf16* ga = Az + (long long)(m0 + lrow) * lda + (k0 + lcol);
        const bf16* gb = Bz + (long long)(n0 + lrow) * ldb + (k0 + lcol);
        gld16(ga, AsW);
        gld16(ga + 64LL * lda, AsW + 4096);
        gld16(gb, BsW);
        gld16(gb + 64LL * ldb, BsW + 4096);
        __syncthreads();

        bf16x8 af[4], bfr[4];
#pragma unroll
        for (int i = 0; i < 4; ++i)
            af[i] = *reinterpret_cast<const bf16x8*>(&As[(wm + i * 16 + fr) * 32 + fq * 8]);
#pragma unroll
        for (int j = 0; j < 4; ++j)
            bfr[j] = *reinterpret_cast<const bf16x8*>(&Bs[(wn + j * 16 + fr) * 32 + fq * 8]);
#pragma unroll
        for (int i = 0; i < 4; ++i)
#pragma unroll
            for (int j = 0; j < 4; ++j)
                acc[i][j] = __builtin_amdgcn_mfma_f32_16x16x32_bf16(af[i], bfr[j], acc[i][j], 0, 0, 0);
        __syncthreads();
    }

#pragma unroll
    for (int j = 0; j < 4; ++j) {
        const int col = n0 + wn + j * 16 + fr;
        const float bv = bias ? bias[col] : 0.f;
#pragma unroll
        for (int i = 0; i < 4; ++i) {
#pragma unroll
            for (int r = 0; r < 4; ++r) {
                const long long row = m0 + wm + i * 16 + fq * 4 + r;
                const float v = acc[i][j][r];
                if constexpr (EPI == 0) {
                    outb[(long long)z * sO + row * N + col] = __float2bfloat16(v * scale + bv);
                } else if constexpr (EPI == 2) {
                    const float pd = v + bv;
                    const float pa = pd + anchor[(row >> 11) * 512 + col];
                    out1[row * N + col] = pd;
                    out2[row * N + col] = pa;
                    outb[row * N + col] = __float2bfloat16(pa);
                } else {
                    outb[(row >> 11) * 1048576LL + (long long)col * 2048 + (row & 2047)]
                        = __float2bfloat16(v + bv);
                }
            }
        }
    }
}

// ---------------------------------------------------------------------------
// Fused softmax + PV (flash-style, logits pre-materialized as bf16).
// Grid: (32 m-tiles of 64 rows, 8 batches), 256 threads (4 waves, N-split 4x128).
// pass 1: per-row max m and sumexp l over 2048 bf16 logits.
// pass 2: loop kv in steps of 32: stage V_t[:,kv..] -> LDS (glds), build P
// A-frags in-register (exp of logits), MFMA into acc (unnormalized), write
// f32 attn = e/l in-flight (wave owns its kv quarter). Epilogue: ctx = acc/l.
// ---------------------------------------------------------------------------
__global__ __launch_bounds__(256)
void k_sv(const bf16* __restrict__ L, const bf16* __restrict__ Vt,
          float* __restrict__ attn, bf16* __restrict__ ctx)
{
    __shared__ short Bs[512 * 32];     // V_t slice [512 n][32 k]
    __shared__ float sm[64], sl[64];   // row max, 1/sumexp
    const int tid = threadIdx.x;
    const int z = blockIdx.y;
    const int m0 = blockIdx.x * 64;
    const bf16* Lz = L + (long long)z * 4194304 + (long long)m0 * 2048;
    const bf16* Vz = Vt + (long long)z * 1048576;
    float* Az = attn + (long long)z * 4194304 + (long long)m0 * 2048;

    // ---- pass 1: online row max / sumexp, 4 threads per row ----
    {
        const int r = tid >> 2, cb = (tid & 3) * 8;
        const bf16* rp = Lz + (long long)r * 2048 + cb;
        float mr = -1e30f, lr = 0.f;
        for (int i = 0; i < 64; ++i) {
            u16x8 u = *reinterpret_cast<const u16x8*>(rp + i * 32);
            float x[8];
#pragma unroll
            for (int j = 0; j < 8; ++j) x[j] = b2f(u[j]);
            float cm = fmaxf(fmaxf(fmaxf(x[0], x[1]), fmaxf(x[2], x[3])),
                             fmaxf(fmaxf(x[4], x[5]), fmaxf(x[6], x[7])));
            if (cm > mr) { lr *= __expf(mr - cm); mr = cm; }
#pragma unroll
            for (int j = 0; j < 8; ++j) lr += __expf(x[j] - mr);
        }
#pragma unroll
        for (int off = 1; off < 4; off <<= 1) {
            float mo = __shfl_xor(mr, off);
            float lo = __shfl_xor(lr, off);
            float mn = fmaxf(mr, mo);
            lr = lr * __expf(mr - mn) + lo * __expf(mo - mn);
            mr = mn;
        }
        if ((tid & 3) == 0) { sm[r] = mr; sl[r] = 1.f / lr; }
    }
    __syncthreads();

    // ---- pass 2 ----
    const int lane = tid & 63, w = tid >> 6;
    const int fr = lane & 15, fq = lane >> 4;
    const int wn = w * 128;
    const int vrow = tid >> 2, vcol = (tid & 3) * 8;

    float mrow[4], irow[4];
#pragma unroll
    for (int mf = 0; mf < 4; ++mf) { mrow[mf] = sm[mf * 16 + fr]; irow[mf] = sl[mf * 16 + fr]; }

    f32x4 acc[4][8];
#pragma unroll
    for (int i = 0; i < 4; ++i)
#pragma unroll
        for (int j = 0; j < 8; ++j) acc[i][j] = f32x4{0.f, 0.f, 0.f, 0.f};

    for (int kv = 0; kv < 2048; kv += 32) {
#pragma unroll
        for (int i = 0; i < 8; ++i)
            gld16(Vz + (long long)(i * 64 + vrow) * 2048 + (kv + vcol),
                  (char*)Bs + i * 4096 + w * 1024);
        __syncthreads();

        bf16x8 bfr[8];
#pragma unroll
        for (int nf = 0; nf < 8; ++nf)
            bfr[nf] = *reinterpret_cast<const bf16x8*>(&Bs[(wn + nf * 16 + fr) * 32 + fq * 8]);

        const bool owner = (kv >> 9) == w;
#pragma unroll
        for (int mf = 0; mf < 4; ++mf) {
            u16x8 u = *reinterpret_cast<const u16x8*>(
                Lz + (long long)(mf * 16 + fr) * 2048 + kv + fq * 8);
            float e[8];
#pragma unroll
            for (int j = 0; j < 8; ++j) e[j] = __expf(b2f(u[j]) - mrow[mf]);
            short pb[8];
#pragma unroll
            for (int j = 0; j < 8; ++j) pb[j] = (short)f2u(e[j]);
            bf16x8 pa = *reinterpret_cast<bf16x8*>(pb);
            if (owner) {
                const float s = irow[mf];
                float* ap = Az + (long long)(mf * 16 + fr) * 2048 + kv + fq * 8;
                *reinterpret_cast<float4*>(ap)     = make_float4(e[0]*s, e[1]*s, e[2]*s, e[3]*s);
                *reinterpret_cast<float4*>(ap + 4) = make_float4(e[4]*s, e[5]*s, e[6]*s, e[7]*s);
            }
#pragma unroll
            for (int nf = 0; nf < 8; ++nf)
                acc[mf][nf] = __builtin_amdgcn_mfma_f32_16x16x32_bf16(pa, bfr[nf], acc[mf][nf], 0, 0, 0);
        }
        __syncthreads();
    }

    // ---- epilogue: ctx = acc / l ----
#pragma unroll
    for (int mf = 0; mf < 4; ++mf)
#pragma unroll
        for (int r = 0; r < 4; ++r) {
            const int rl = mf * 16 + fq * 4 + r;
            const float s = sl[rl];
            const long long grow = (long long)z * 2048 + m0 + rl;
#pragma unroll
            for (int nf = 0; nf < 8; ++nf)
                ctx[grow * 512 + wn + nf * 16 + fr] = __float2bfloat16(acc[mf][nf][r] * s);
        }
}

// ---------------------------------------------------------------------------
// Concat-gather MFMA GEMM (gate MLPs): A cols [0,2048) from 4 bf16 sources of
// 512 each (mode2=1: src2 = anchor_b[B,512] broadcast). Bt bf16 [512][2048].
// Epilogue: bf16 relu(acc+bias) -> whid_b.  M=16384, N=512, K=2048.
// ---------------------------------------------------------------------------
__global__ __launch_bounds__(256)
void k_cat(const bf16* __restrict__ s0b, const bf16* __restrict__ s1b,
           const bf16* __restrict__ s2b, const bf16* __restrict__ s3b,
           int mode2,
           const bf16* __restrict__ Bt, const float* __restrict__ bias,
           bf16* __restrict__ outb)
{
    __shared__ short As[4096];
    __shared__ short Bs[4096];
    const int tid = threadIdx.x;
    const int n0 = blockIdx.x * 128, m0 = blockIdx.y * 128;
    const int lrow = tid >> 2;
    const int lcol = (tid & 3) * 8;
    const int lane = tid & 63, w = tid >> 6;
    const int wm = (w >> 1) * 64, wn = (w & 1) * 64;
    const int fr = lane & 15, fq = lane >> 4;
    char* AsW = (char*)As + w * 1024;
    char* BsW = (char*)Bs + w * 1024;

    f32x4 acc[4][4];
#pragma unroll
    for (int i = 0; i < 4; ++i)
#pragma unroll
        for (int j = 0; j < 4; ++j) acc[i][j] = f32x4{0.f, 0.f, 0.f, 0.f};

    for (int k0 = 0; k0 < 2048; k0 += 32) {
        const int si = k0 >> 9;
        const bf16* sp = si == 0 ? s0b : si == 1 ? s1b : si == 2 ? s2b : s3b;
        const int kloc = (k0 & 511) + lcol;
        const int r = m0 + lrow;
        long long ro0, ro1;
        if (si == 2 && mode2) { ro0 = (long long)(r >> 11) * 512; ro1 = ro0; }
        else                  { ro0 = (long long)r * 512; ro1 = ro0 + 64LL * 512; }
        gld16(sp + ro0 + kloc, AsW);
        gld16(sp + ro1 + kloc, AsW + 4096);
        const bf16* gb = Bt + (long long)(n0 + lrow) * 2048 + (k0 + lcol);
        gld16(gb, BsW);
        gld16(gb + 64LL * 2048, BsW + 4096);
        __syncthreads();

        bf16x8 af[4], bfr[4];
#pragma unroll
        for (int i = 0; i < 4; ++i)
            af[i] = *reinterpret_cast<const bf16x8*>(&As[(wm + i * 16 + fr) * 32 + fq * 8]);
#pragma unroll
        for (int j = 0; j < 4; ++j)
            bfr[j] = *reinterpret_cast<const bf16x8*>(&Bs[(wn + j * 16 + fr) * 32 + fq * 8]);
#pragma unroll
        for (int i = 0; i < 4; ++i)
#pragma unroll
            for (int j = 0; j < 4; ++j)
                acc[i][j] = __builtin_amdgcn_mfma_f32_16x16x32_bf16(af[i], bfr[j], acc[i][j], 0, 0, 0);
        __syncthreads();
    }

#pragma unroll
    for (int j = 0; j < 4; ++j) {
        const int col = n0 + wn + j * 16 + fr;
        const float bv = bias[col];
#pragma unroll
        for (int i = 0; i < 4; ++i)
#pragma unroll
            for (int r = 0; r < 4; ++r) {
                const long long row = m0 + wm + i * 16 + fq * 4 + r;
                outb[row * 512 + col] = __float2bfloat16(fmaxf(acc[i][j][r] + bv, 0.f));
            }
    }
}

// ---------------------------------------------------------------------------
// f32 -> bf16 elementwise convert, 8/thread. n multiple of 2048.
// ---------------------------------------------------------------------------
__global__ __launch_bounds__(256)
void k_cvt(const float* __restrict__ s, bf16* __restrict__ d, int n)
{
    long long i = ((long long)blockIdx.x * 256 + threadIdx.x) * 8;
    if (i >= n) return;
    float x[8]; load8f(s + i, x);
    u16x8 o;
#pragma unroll
    for (int j = 0; j < 8; ++j) o[j] = f2u(x[j]);
    *reinterpret_cast<u16x8*>(d + i) = o;
}

// ---------------------------------------------------------------------------
// Transposing convert: src f32 [R][C] -> dst bf16 [C][R]. 32x32 tiles.
// ---------------------------------------------------------------------------
__global__ __launch_bounds__(256)
void k_tr(const float* s0, bf16* d0, const float* s1, bf16* d1,
          const float* s2, bf16* d2, const float* s3, bf16* d3,
          int R, int C)
{
    __shared__ float t[32][33];
    const int zz = blockIdx.z;
    const float* s = zz == 0 ? s0 : zz == 1 ? s1 : zz == 2 ? s2 : s3;
    bf16* d = zz == 0 ? d0 : zz == 1 ? d1 : zz == 2 ? d2 : d3;
    const int c0 = blockIdx.x * 32, r0 = blockIdx.y * 32;
    const int tr = threadIdx.x >> 3, tc = (threadIdx.x & 7) * 4;
    float4 v = *reinterpret_cast<const float4*>(s + (long long)(r0 + tr) * C + c0 + tc);
    t[tr][tc] = v.x; t[tr][tc + 1] = v.y; t[tr][tc + 2] = v.z; t[tr][tc + 3] = v.w;
    __syncthreads();
    u16x4v o;
    o[0] = f2u(t[tc + 0][tr]); o[1] = f2u(t[tc + 1][tr]);
    o[2] = f2u(t[tc + 2][tr]); o[3] = f2u(t[tc + 3][tr]);
    *reinterpret_cast<u16x4v*>(d + (long long)(c0 + tr) * R + r0 + tc) = o;
}

// ---------------------------------------------------------------------------
// Gate GEMV over bf16 hidden: logit = hidden[row,:512] . w2 + b2. One wave/row.
// ---------------------------------------------------------------------------
__global__ __launch_bounds__(64)
void k_gate(const bf16* __restrict__ hidden, const float* __restrict__ w2,
            const float* __restrict__ b2,
            float* __restrict__ outLogit, float* __restrict__ outGate,
            float scl, float add)
{
    const long long row = blockIdx.x;
    const int lane = threadIdx.x;
    u16x8 u = *reinterpret_cast<const u16x8*>(hidden + row * 512 + lane * 8);
    float wv[8];
    load8f(w2 + lane * 8, wv);
    float s = 0.f;
#pragma unroll
    for (int j = 0; j < 8; ++j) s = fmaf(b2f(u[j]), wv[j], s);
#pragma unroll
    for (int off = 32; off; off >>= 1) s += __shfl_xor(s, off);
    if (lane == 0) {
        float logit = s + b2[0];
        if (outLogit) outLogit[row] = logit;
        outGate[row] = sigmoidf_(logit * scl + add);
    }
}

// ---------------------------------------------------------------------------
// Slerp: one wave per row. a=pa_b(bf16), b=local_b(bf16). Emits f32 cand/cdelta
// + bf16 cand (written in-place over pa_b slot).
// ---------------------------------------------------------------------------
__global__ __launch_bounds__(64)
void k_slerp(const bf16* __restrict__ priorb, const bf16* __restrict__ localb,
             const float* __restrict__ mixv, const float* __restrict__ anchor,
             float* __restrict__ cand, float* __restrict__ cdelta,
             bf16* __restrict__ candb)
{
    const int row = blockIdx.x;
    const int lane = threadIdx.x;
    const long long base = (long long)row * 512 + lane * 8;
    const long long abase = (long long)(row >> 11) * 512 + lane * 8;

    u16x8 ua = *reinterpret_cast<const u16x8*>(priorb + base);
    u16x8 ub = *reinterpret_cast<const u16x8*>(localb + base);
    float a[8], b[8];
    float sa = 0.f, sb = 0.f, sab = 0.f;
#pragma unroll
    for (int j = 0; j < 8; ++j) {
        a[j] = b2f(ua[j]); b[j] = b2f(ub[j]);
        sa = fmaf(a[j], a[j], sa); sb = fmaf(b[j], b[j], sb); sab = fmaf(a[j], b[j], sab);
    }
#pragma unroll
    for (int off = 1; off < 64; off <<= 1) {
        sa += __shfl_xor(sa, off); sb += __shfl_xor(sb, off); sab += __shfl_xor(sab, off);
    }
    const float eps = 1e-6f;
    float na = fmaxf(sqrtf(sa), eps), nb = fmaxf(sqrtf(sb), eps);
    float dot = sab / (na * nb);
    dot = fminf(fmaxf(dot, -1.f + eps), 1.f - eps);
    float omega = acosf(dot);
    float so = fmaxf(sinf(omega), eps);
    float t = mixv[row];
    t = fminf(fmaxf(t, 0.f), 1.f);
    float sca = sinf((1.f - t) * omega) / so;
    float scb = sinf(t * omega) / so;

    float an[8];
    load8f(anchor + abase, an);
    float c0[8], d0[8];
    u16x8 cb;
#pragma unroll
    for (int j = 0; j < 8; ++j) {
        c0[j] = sca * a[j] + scb * b[j];
        d0[j] = c0[j] - an[j];
        cb[j] = f2u(c0[j]);
    }
    *reinterpret_cast<float4*>(cand + base)       = make_float4(c0[0], c0[1], c0[2], c0[3]);
    *reinterpret_cast<float4*>(cand + base + 4)   = make_float4(c0[4], c0[5], c0[6], c0[7]);
    *reinterpret_cast<float4*>(cdelta + base)     = make_float4(d0[0], d0[1], d0[2], d0[3]);
    *reinterpret_cast<float4*>(cdelta + base + 4) = make_float4(d0[4], d0[5], d0[6], d0[7]);
    *reinterpret_cast<u16x8*>(candb + base) = cb;
}

// ---------------------------------------------------------------------------
extern "C" void kernel_launch(void* const* d_in, const int* in_sizes, int n_in,
                              void* d_out, int out_size, void* d_ws, size_t ws_size,
                              hipStream_t stream)
{
    const float* query  = (const float*)d_in[0];
    const float* anchor = (const float*)d_in[1];
    const float* gmem   = (const float*)d_in[2];
    const float* local_ = (const float*)d_in[3];
    const float* style  = (const float*)d_in[4];
    const float* Wq = (const float*)d_in[5];   const float* bq = (const float*)d_in[6];
    const float* Wk = (const float*)d_in[7];   const float* bk = (const float*)d_in[8];
    const float* Wv = (const float*)d_in[9];   const float* bv = (const float*)d_in[10];
    const float* Wo = (const float*)d_in[11];  const float* bo = (const float*)d_in[12];
    const float* Wm1 = (const float*)d_in[13]; const float* bm1 = (const float*)d_in[14];
    const float* Wm2 = (const float*)d_in[15]; const float* bm2 = (const float*)d_in[16];
    const float* Wg1 = (const float*)d_in[17]; const float* bg1 = (const float*)d_in[18];
    const float* Wg2 = (const float*)d_in[19]; const float* bg2 = (const float*)d_in[20];

    float* out = (float*)d_out;
    const long long SHE = 8388608LL;             // B*S*H elems
    float* o_attn = out;                         // [B,S,M]
    float* o_pd   = out + 33554432LL;            // prior_delta
    float* o_pa   = o_pd + SHE;                  // prior_absolute
    float* o_mix  = o_pa + SHE;                  // mix [16384]
    float* o_ca   = o_mix + 16384;               // candidate_absolute
    float* o_cd   = o_ca + SHE;                  // candidate_delta
    float* o_vl   = o_cd + SHE;                  // variation_logit
    float* o_vg   = o_vl + 16384;                // variation_gate

    // ws slots (bf16, 8.4M elems each, aggressively reused):
    bf16* S0q = (bf16*)d_ws;       // query_b (whole run)
    bf16* S1  = S0q + SHE;         // gmem_b -> ctx_b -> whid_b
    bf16* S2  = S1 + SHE;          // q_b -> pa_b -> ca_b
    bf16* S3  = S2 + SHE;          // k_b -> local_b
    bf16* S4  = S3 + SHE;          // v_t -> style_b
    bf16* wtq = S4 + SHE;          // transposed weights (bf16)
    bf16* wtk = wtq + 262144;
    bf16* wtv = wtk + 262144;
    bf16* wto = wtv + 262144;
    bf16* wtm1 = wto + 262144;     // [512][2048]
    bf16* wtg1 = wtm1 + 1048576;   // [512][2048]
    bf16* anb  = wtg1 + 1048576;   // anchor_b [8,512]
    bf16* p_b  = (bf16*)o_ca;      // bf16 logits in not-yet-written d_out (67 MB)

    const float invSqrtH = 0.04419417382415922f; // 1/sqrt(512)

    // prologue: bf16 conversions + weight transposes
    k_cvt<<<4096, 256, 0, stream>>>(query, S0q, 8388608);
    k_cvt<<<4096, 256, 0, stream>>>(gmem, S1, 8388608);
    k_cvt<<<2, 256, 0, stream>>>(anchor, anb, 4096);
    k_tr<<<dim3(16, 16, 4), 256, 0, stream>>>(Wq, wtq, Wk, wtk, Wv, wtv, Wo, wto, 512, 512);
    k_tr<<<dim3(16, 64, 2), 256, 0, stream>>>(Wm1, wtm1, Wg1, wtg1,
                                              nullptr, nullptr, nullptr, nullptr, 2048, 512);
    // q,k,v projections (v written transposed per batch)
    k_mfma<0><<<dim3(4, 128, 1), 256, 0, stream>>>(S0q, 0, 512, wtq, 0, 512, bq,
        S2, 0, nullptr, nullptr, nullptr, 512, 512, 1.f);
    k_mfma<0><<<dim3(4, 128, 1), 256, 0, stream>>>(S1, 0, 512, wtk, 0, 512, bk,
        S3, 0, nullptr, nullptr, nullptr, 512, 512, 1.f);
    k_mfma<3><<<dim3(4, 128, 1), 256, 0, stream>>>(S1, 0, 512, wtv, 0, 512, bv,
        S4, 0, nullptr, nullptr, nullptr, 512, 512, 1.f);
    // attention logits (NT): q_b . k_b^T * scale -> bf16 p_b
    k_mfma<0><<<dim3(16, 16, 8), 256, 0, stream>>>(S2, 2048LL * 512, 512, S3, 2048LL * 512, 512,
        nullptr, p_b, 4194304LL, nullptr, nullptr, nullptr, 2048, 512, invSqrtH);
    // fused softmax + PV: p_b, v_t -> attn f32 + ctx_b (S1; gmem_b dead)
    k_sv<<<dim3(32, 8, 1), 256, 0, stream>>>(p_b, S4, o_attn, S1);
    // free slots S3/S4 -> convert local/style
    k_cvt<<<4096, 256, 0, stream>>>(local_, S3, 8388608);
    k_cvt<<<4096, 256, 0, stream>>>(style, S4, 8388608);
    // Wo projection + prior epilogue (pd, pa, pa_b -> S2)
    k_mfma<2><<<dim3(4, 128, 1), 256, 0, stream>>>(S1, 0, 512, wto, 0, 512, bo,
        S2, 0, o_pd, o_pa, anchor, 512, 512, 1.f);
    // mix gate MLP (whid_b -> S1; ctx_b dead)
    k_cat<<<dim3(4, 128, 1), 256, 0, stream>>>(S0q, S2, S3, S4, 0, wtm1, bm1, S1);
    k_gate<<<16384, 64, 0, stream>>>(S1, Wm2, bm2, nullptr, o_mix, 1.0f, -0.25f);
    // slerp (bf16 inputs) -> candidate_absolute/delta f32 (+ca_b in-place S2)
    // NOTE: overwrites o_ca/o_cd which held p_b -- p_b dead after k_sv.
    k_slerp<<<16384, 64, 0, stream>>>(S2, S3, o_mix, anchor, o_ca, o_cd, S2);
    // variation gate MLP (src2 = anchor_b broadcast)
    k_cat<<<dim3(4, 128, 1), 256, 0, stream>>>(S0q, S2, anb, S4, 1, wtg1, bg1, S1);
    k_gate<<<16384, 64, 0, stream>>>(S1, Wg2, bg2, o_vl, o_vg, 1.0f, -1.0f);
}

// Round 6
// 481.137 us; speedup vs baseline: 1.1367x; 1.1367x over previous
//
#include <hip/hip_runtime.h>
#include <hip/hip_bf16.h>

typedef __hip_bfloat16 bf16;
typedef unsigned short u16;
typedef u16 u16x8 __attribute__((ext_vector_type(8)));
typedef u16 u16x4v __attribute__((ext_vector_type(4)));
typedef short bf16x8 __attribute__((ext_vector_type(8)));
typedef float f32x4 __attribute__((ext_vector_type(4)));

__device__ __forceinline__ float b2f(u16 u) {
    unsigned v = ((unsigned)u) << 16;
    float f; __builtin_memcpy(&f, &v, 4); return f;
}
__device__ __forceinline__ u16 f2u(float f) {
    bf16 h = __float2bfloat16(f);
    u16 u; __builtin_memcpy(&u, &h, 2); return u;
}
__device__ __forceinline__ float sigmoidf_(float x) { return 1.f / (1.f + expf(-x)); }
__device__ __forceinline__ void load8f(const float* __restrict__ p, float* x) {
    float4 a = *reinterpret_cast<const float4*>(p);
    float4 b = *reinterpret_cast<const float4*>(p + 4);
    x[0]=a.x; x[1]=a.y; x[2]=a.z; x[3]=a.w; x[4]=b.x; x[5]=b.y; x[6]=b.z; x[7]=b.w;
}

// async global->LDS, 16B per lane. LDS dest = wave-uniform base + lane*16.
__device__ __forceinline__ void gld16(const void* g, void* l) {
    typedef __attribute__((address_space(1))) const unsigned int GU;
    typedef __attribute__((address_space(3))) unsigned int LU;
    __builtin_amdgcn_global_load_lds((GU*)(unsigned long long)g,
                                     (LU*)(unsigned int)(unsigned long long)l, 16, 0, 0);
}

// ---------------------------------------------------------------------------
// m97-structure MFMA GEMM: C = A[m][k] . Bt[n][k]^T, batched over z.
// 128x128 tile, BK=32, 256 thr (4 waves 2x2), global_load_lds, linear LDS.
// EPI 0: bf16 outb = acc*scale + bias, stride sO per z
// EPI 2: Wo: out1=pd=acc+bias; out2=pa=pd+anchor; outb=bf16(pa)   (z=0)
// EPI 3: v_t: outb[(row>>11)*2048*512 + col*2048 + (row&2047)] = bf16(acc+bias)
// ---------------------------------------------------------------------------
template<int EPI>
__global__ __launch_bounds__(256)
void k_mfma(const bf16* __restrict__ A, long long sA, int lda,
            const bf16* __restrict__ Bt, long long sB, int ldb,
            const float* __restrict__ bias,
            bf16* __restrict__ outb, long long sO,
            float* __restrict__ out1, float* __restrict__ out2,
            const float* __restrict__ anchor,
            int N, int K, float scale)
{
    __shared__ short As[4096];
    __shared__ short Bs[4096];
    const int tid = threadIdx.x;
    const int z = blockIdx.z;
    const int n0 = blockIdx.x * 128, m0 = blockIdx.y * 128;
    const bf16* Az = A + (long long)z * sA;
    const bf16* Bz = Bt + (long long)z * sB;
    const int lrow = tid >> 2;          // 0..63 staging row
    const int lcol = (tid & 3) * 8;     // k-chunk within 32
    const int lane = tid & 63, w = tid >> 6;
    const int wm = (w >> 1) * 64, wn = (w & 1) * 64;
    const int fr = lane & 15, fq = lane >> 4;
    char* AsW = (char*)As + w * 1024;   // wave-uniform LDS staging base
    char* BsW = (char*)Bs + w * 1024;

    f32x4 acc[4][4];
#pragma unroll
    for (int i = 0; i < 4; ++i)
#pragma unroll
        for (int j = 0; j < 4; ++j) acc[i][j] = f32x4{0.f, 0.f, 0.f, 0.f};

    for (int k0 = 0; k0 < K; k0 += 32) {
        const bf16* ga = Az + (long long)(m0 + lrow) * lda + (k0 + lcol);
        const bf16* gb = Bz + (long long)(n0 + lrow) * ldb + (k0 + lcol);
        gld16(ga, AsW);
        gld16(ga + 64LL * lda, AsW + 4096);
        gld16(gb, BsW);
        gld16(gb + 64LL * ldb, BsW + 4096);
        __syncthreads();

        bf16x8 af[4], bfr[4];
#pragma unroll
        for (int i = 0; i < 4; ++i)
            af[i] = *reinterpret_cast<const bf16x8*>(&As[(wm + i * 16 + fr) * 32 + fq * 8]);
#pragma unroll
        for (int j = 0; j < 4; ++j)
            bfr[j] = *reinterpret_cast<const bf16x8*>(&Bs[(wn + j * 16 + fr) * 32 + fq * 8]);
#pragma unroll
        for (int i = 0; i < 4; ++i)
#pragma unroll
            for (int j = 0; j < 4; ++j)
                acc[i][j] = __builtin_amdgcn_mfma_f32_16x16x32_bf16(af[i], bfr[j], acc[i][j], 0, 0, 0);
        __syncthreads();
    }

#pragma unroll
    for (int j = 0; j < 4; ++j) {
        const int col = n0 + wn + j * 16 + fr;
        const float bv = bias ? bias[col] : 0.f;
#pragma unroll
        for (int i = 0; i < 4; ++i) {
#pragma unroll
            for (int r = 0; r < 4; ++r) {
                const long long row = m0 + wm + i * 16 + fq * 4 + r;
                const float v = acc[i][j][r];
                if constexpr (EPI == 0) {
                    outb[(long long)z * sO + row * N + col] = __float2bfloat16(v * scale + bv);
                } else if constexpr (EPI == 2) {
                    const float pd = v + bv;
                    const float pa = pd + anchor[(row >> 11) * 512 + col];
                    out1[row * N + col] = pd;
                    out2[row * N + col] = pa;
                    outb[row * N + col] = __float2bfloat16(pa);
                } else {
                    outb[(row >> 11) * 1048576LL + (long long)col * 2048 + (row & 2047)]
                        = __float2bfloat16(v + bv);
                }
            }
        }
    }
}

// ---------------------------------------------------------------------------
// Softmax over bf16 logit rows of 2048 (one block/row, 256 thr):
// reads bf16 logits, writes f32 attn and normalized bf16 P in-place over
// the logit buffer.
// ---------------------------------------------------------------------------
__global__ __launch_bounds__(256)
void k_softmax_b(bf16* __restrict__ Lb, float* __restrict__ attn)
{
    __shared__ float redm[4], reds[4];
    const long long row = blockIdx.x;
    bf16* lp = Lb + row * 2048;
    float* ap = attn + row * 2048;
    const int tid = threadIdx.x;

    u16x8 u = *reinterpret_cast<const u16x8*>(lp + tid * 8);
    float x[8];
    float mx = -1e30f;
#pragma unroll
    for (int j = 0; j < 8; ++j) { x[j] = b2f(u[j]); mx = fmaxf(mx, x[j]); }
#pragma unroll
    for (int off = 32; off; off >>= 1) mx = fmaxf(mx, __shfl_xor(mx, off));
    if ((tid & 63) == 0) redm[tid >> 6] = mx;
    __syncthreads();
    mx = fmaxf(fmaxf(redm[0], redm[1]), fmaxf(redm[2], redm[3]));

    float s = 0.f;
#pragma unroll
    for (int j = 0; j < 8; ++j) { x[j] = __expf(x[j] - mx); s += x[j]; }
#pragma unroll
    for (int off = 32; off; off >>= 1) s += __shfl_xor(s, off);
    if ((tid & 63) == 0) reds[tid >> 6] = s;
    __syncthreads();
    const float inv = 1.f / (reds[0] + reds[1] + reds[2] + reds[3]);

    u16x8 ob;
#pragma unroll
    for (int j = 0; j < 8; ++j) { x[j] *= inv; ob[j] = f2u(x[j]); }
    *reinterpret_cast<float4*>(ap + tid * 8)     = make_float4(x[0], x[1], x[2], x[3]);
    *reinterpret_cast<float4*>(ap + tid * 8 + 4) = make_float4(x[4], x[5], x[6], x[7]);
    *reinterpret_cast<u16x8*>(lp + tid * 8) = ob;
}

// ---------------------------------------------------------------------------
// Concat-gather MFMA GEMM (gate MLPs): A cols [0,2048) from 4 bf16 sources of
// 512 each (mode2=1: src2 = anchor_b[B,512] broadcast). Bt bf16 [512][2048].
// Epilogue: bf16 relu(acc+bias) -> whid_b.  M=16384, N=512, K=2048.
// ---------------------------------------------------------------------------
__global__ __launch_bounds__(256)
void k_cat(const bf16* __restrict__ s0b, const bf16* __restrict__ s1b,
           const bf16* __restrict__ s2b, const bf16* __restrict__ s3b,
           int mode2,
           const bf16* __restrict__ Bt, const float* __restrict__ bias,
           bf16* __restrict__ outb)
{
    __shared__ short As[4096];
    __shared__ short Bs[4096];
    const int tid = threadIdx.x;
    const int n0 = blockIdx.x * 128, m0 = blockIdx.y * 128;
    const int lrow = tid >> 2;
    const int lcol = (tid & 3) * 8;
    const int lane = tid & 63, w = tid >> 6;
    const int wm = (w >> 1) * 64, wn = (w & 1) * 64;
    const int fr = lane & 15, fq = lane >> 4;
    char* AsW = (char*)As + w * 1024;
    char* BsW = (char*)Bs + w * 1024;

    f32x4 acc[4][4];
#pragma unroll
    for (int i = 0; i < 4; ++i)
#pragma unroll
        for (int j = 0; j < 4; ++j) acc[i][j] = f32x4{0.f, 0.f, 0.f, 0.f};

    for (int k0 = 0; k0 < 2048; k0 += 32) {
        const int si = k0 >> 9;
        const bf16* sp = si == 0 ? s0b : si == 1 ? s1b : si == 2 ? s2b : s3b;
        const int kloc = (k0 & 511) + lcol;
        const int r = m0 + lrow;
        long long ro0, ro1;
        if (si == 2 && mode2) { ro0 = (long long)(r >> 11) * 512; ro1 = ro0; }
        else                  { ro0 = (long long)r * 512; ro1 = ro0 + 64LL * 512; }
        gld16(sp + ro0 + kloc, AsW);
        gld16(sp + ro1 + kloc, AsW + 4096);
        const bf16* gb = Bt + (long long)(n0 + lrow) * 2048 + (k0 + lcol);
        gld16(gb, BsW);
        gld16(gb + 64LL * 2048, BsW + 4096);
        __syncthreads();

        bf16x8 af[4], bfr[4];
#pragma unroll
        for (int i = 0; i < 4; ++i)
            af[i] = *reinterpret_cast<const bf16x8*>(&As[(wm + i * 16 + fr) * 32 + fq * 8]);
#pragma unroll
        for (int j = 0; j < 4; ++j)
            bfr[j] = *reinterpret_cast<const bf16x8*>(&Bs[(wn + j * 16 + fr) * 32 + fq * 8]);
#pragma unroll
        for (int i = 0; i < 4; ++i)
#pragma unroll
            for (int j = 0; j < 4; ++j)
                acc[i][j] = __builtin_amdgcn_mfma_f32_16x16x32_bf16(af[i], bfr[j], acc[i][j], 0, 0, 0);
        __syncthreads();
    }

#pragma unroll
    for (int j = 0; j < 4; ++j) {
        const int col = n0 + wn + j * 16 + fr;
        const float bv = bias[col];
#pragma unroll
        for (int i = 0; i < 4; ++i)
#pragma unroll
            for (int r = 0; r < 4; ++r) {
                const long long row = m0 + wm + i * 16 + fq * 4 + r;
                outb[row * 512 + col] = __float2bfloat16(fmaxf(acc[i][j][r] + bv, 0.f));
            }
    }
}

// ---------------------------------------------------------------------------
// f32 -> bf16 elementwise convert, 8/thread. n multiple of 2048.
// ---------------------------------------------------------------------------
__global__ __launch_bounds__(256)
void k_cvt(const float* __restrict__ s, bf16* __restrict__ d, int n)
{
    long long i = ((long long)blockIdx.x * 256 + threadIdx.x) * 8;
    if (i >= n) return;
    float x[8]; load8f(s + i, x);
    u16x8 o;
#pragma unroll
    for (int j = 0; j < 8; ++j) o[j] = f2u(x[j]);
    *reinterpret_cast<u16x8*>(d + i) = o;
}

// ---------------------------------------------------------------------------
// Transposing convert: src f32 [R][C] -> dst bf16 [C][R]. 32x32 tiles.
// ---------------------------------------------------------------------------
__global__ __launch_bounds__(256)
void k_tr(const float* s0, bf16* d0, const float* s1, bf16* d1,
          const float* s2, bf16* d2, const float* s3, bf16* d3,
          int R, int C)
{
    __shared__ float t[32][33];
    const int zz = blockIdx.z;
    const float* s = zz == 0 ? s0 : zz == 1 ? s1 : zz == 2 ? s2 : s3;
    bf16* d = zz == 0 ? d0 : zz == 1 ? d1 : zz == 2 ? d2 : d3;
    const int c0 = blockIdx.x * 32, r0 = blockIdx.y * 32;
    const int tr = threadIdx.x >> 3, tc = (threadIdx.x & 7) * 4;
    float4 v = *reinterpret_cast<const float4*>(s + (long long)(r0 + tr) * C + c0 + tc);
    t[tr][tc] = v.x; t[tr][tc + 1] = v.y; t[tr][tc + 2] = v.z; t[tr][tc + 3] = v.w;
    __syncthreads();
    u16x4v o;
    o[0] = f2u(t[tc + 0][tr]); o[1] = f2u(t[tc + 1][tr]);
    o[2] = f2u(t[tc + 2][tr]); o[3] = f2u(t[tc + 3][tr]);
    *reinterpret_cast<u16x4v*>(d + (long long)(c0 + tr) * R + r0 + tc) = o;
}

// ---------------------------------------------------------------------------
// Gate GEMV over bf16 hidden: logit = hidden[row,:512] . w2 + b2. One wave/row.
// ---------------------------------------------------------------------------
__global__ __launch_bounds__(64)
void k_gate(const bf16* __restrict__ hidden, const float* __restrict__ w2,
            const float* __restrict__ b2,
            float* __restrict__ outLogit, float* __restrict__ outGate,
            float scl, float add)
{
    const long long row = blockIdx.x;
    const int lane = threadIdx.x;
    u16x8 u = *reinterpret_cast<const u16x8*>(hidden + row * 512 + lane * 8);
    float wv[8];
    load8f(w2 + lane * 8, wv);
    float s = 0.f;
#pragma unroll
    for (int j = 0; j < 8; ++j) s = fmaf(b2f(u[j]), wv[j], s);
#pragma unroll
    for (int off = 32; off; off >>= 1) s += __shfl_xor(s, off);
    if (lane == 0) {
        float logit = s + b2[0];
        if (outLogit) outLogit[row] = logit;
        outGate[row] = sigmoidf_(logit * scl + add);
    }
}

// ---------------------------------------------------------------------------
// Slerp: one wave per row. a=pa_b(bf16), b=local_b(bf16). Emits f32 cand/cdelta
// + bf16 cand (written in-place over pa_b slot).
// ---------------------------------------------------------------------------
__global__ __launch_bounds__(64)
void k_slerp(const bf16* __restrict__ priorb, const bf16* __restrict__ localb,
             const float* __restrict__ mixv, const float* __restrict__ anchor,
             float* __restrict__ cand, float* __restrict__ cdelta,
             bf16* __restrict__ candb)
{
    const int row = blockIdx.x;
    const int lane = threadIdx.x;
    const long long base = (long long)row * 512 + lane * 8;
    const long long abase = (long long)(row >> 11) * 512 + lane * 8;

    u16x8 ua = *reinterpret_cast<const u16x8*>(priorb + base);
    u16x8 ub = *reinterpret_cast<const u16x8*>(localb + base);
    float a[8], b[8];
    float sa = 0.f, sb = 0.f, sab = 0.f;
#pragma unroll
    for (int j = 0; j < 8; ++j) {
        a[j] = b2f(ua[j]); b[j] = b2f(ub[j]);
        sa = fmaf(a[j], a[j], sa); sb = fmaf(b[j], b[j], sb); sab = fmaf(a[j], b[j], sab);
    }
#pragma unroll
    for (int off = 1; off < 64; off <<= 1) {
        sa += __shfl_xor(sa, off); sb += __shfl_xor(sb, off); sab += __shfl_xor(sab, off);
    }
    const float eps = 1e-6f;
    float na = fmaxf(sqrtf(sa), eps), nb = fmaxf(sqrtf(sb), eps);
    float dot = sab / (na * nb);
    dot = fminf(fmaxf(dot, -1.f + eps), 1.f - eps);
    float omega = acosf(dot);
    float so = fmaxf(sinf(omega), eps);
    float t = mixv[row];
    t = fminf(fmaxf(t, 0.f), 1.f);
    float sca = sinf((1.f - t) * omega) / so;
    float scb = sinf(t * omega) / so;

    float an[8];
    load8f(anchor + abase, an);
    float c0[8], d0[8];
    u16x8 cb;
#pragma unroll
    for (int j = 0; j < 8; ++j) {
        c0[j] = sca * a[j] + scb * b[j];
        d0[j] = c0[j] - an[j];
        cb[j] = f2u(c0[j]);
    }
    *reinterpret_cast<float4*>(cand + base)       = make_float4(c0[0], c0[1], c0[2], c0[3]);
    *reinterpret_cast<float4*>(cand + base + 4)   = make_float4(c0[4], c0[5], c0[6], c0[7]);
    *reinterpret_cast<float4*>(cdelta + base)     = make_float4(d0[0], d0[1], d0[2], d0[3]);
    *reinterpret_cast<float4*>(cdelta + base + 4) = make_float4(d0[4], d0[5], d0[6], d0[7]);
    *reinterpret_cast<u16x8*>(candb + base) = cb;
}

// ---------------------------------------------------------------------------
extern "C" void kernel_launch(void* const* d_in, const int* in_sizes, int n_in,
                              void* d_out, int out_size, void* d_ws, size_t ws_size,
                              hipStream_t stream)
{
    const float* query  = (const float*)d_in[0];
    const float* anchor = (const float*)d_in[1];
    const float* gmem   = (const float*)d_in[2];
    const float* local_ = (const float*)d_in[3];
    const float* style  = (const float*)d_in[4];
    const float* Wq = (const float*)d_in[5];   const float* bq = (const float*)d_in[6];
    const float* Wk = (const float*)d_in[7];   const float* bk = (const float*)d_in[8];
    const float* Wv = (const float*)d_in[9];   const float* bv = (const float*)d_in[10];
    const float* Wo = (const float*)d_in[11];  const float* bo = (const float*)d_in[12];
    const float* Wm1 = (const float*)d_in[13]; const float* bm1 = (const float*)d_in[14];
    const float* Wm2 = (const float*)d_in[15]; const float* bm2 = (const float*)d_in[16];
    const float* Wg1 = (const float*)d_in[17]; const float* bg1 = (const float*)d_in[18];
    const float* Wg2 = (const float*)d_in[19]; const float* bg2 = (const float*)d_in[20];

    float* out = (float*)d_out;
    const long long SHE = 8388608LL;             // B*S*H elems
    float* o_attn = out;                         // [B,S,M]
    float* o_pd   = out + 33554432LL;            // prior_delta
    float* o_pa   = o_pd + SHE;                  // prior_absolute
    float* o_mix  = o_pa + SHE;                  // mix [16384]
    float* o_ca   = o_mix + 16384;               // candidate_absolute
    float* o_cd   = o_ca + SHE;                  // candidate_delta
    float* o_vl   = o_cd + SHE;                  // variation_logit
    float* o_vg   = o_vl + 16384;                // variation_gate

    // ws slots (bf16, 8.4M elems each, aggressively reused):
    bf16* S0q = (bf16*)d_ws;       // query_b (whole run)
    bf16* S1  = S0q + SHE;         // gmem_b -> ctx_b -> whid_b
    bf16* S2  = S1 + SHE;          // q_b -> pa_b -> ca_b
    bf16* S3  = S2 + SHE;          // k_b -> local_b
    bf16* S4  = S3 + SHE;          // v_t -> style_b
    bf16* wtq = S4 + SHE;          // transposed weights (bf16)
    bf16* wtk = wtq + 262144;
    bf16* wtv = wtk + 262144;
    bf16* wto = wtv + 262144;
    bf16* wtm1 = wto + 262144;     // [512][2048]
    bf16* wtg1 = wtm1 + 1048576;   // [512][2048]
    bf16* anb  = wtg1 + 1048576;   // anchor_b [8,512]
    bf16* p_b  = (bf16*)o_ca;      // bf16 logits->P in not-yet-written d_out (67 MB)

    const float invSqrtH = 0.04419417382415922f; // 1/sqrt(512)

    // prologue: bf16 conversions + weight transposes
    k_cvt<<<4096, 256, 0, stream>>>(query, S0q, 8388608);
    k_cvt<<<4096, 256, 0, stream>>>(gmem, S1, 8388608);
    k_cvt<<<2, 256, 0, stream>>>(anchor, anb, 4096);
    k_tr<<<dim3(16, 16, 4), 256, 0, stream>>>(Wq, wtq, Wk, wtk, Wv, wtv, Wo, wto, 512, 512);
    k_tr<<<dim3(16, 64, 2), 256, 0, stream>>>(Wm1, wtm1, Wg1, wtg1,
                                              nullptr, nullptr, nullptr, nullptr, 2048, 512);
    // q,k,v projections (v written transposed per batch)
    k_mfma<0><<<dim3(4, 128, 1), 256, 0, stream>>>(S0q, 0, 512, wtq, 0, 512, bq,
        S2, 0, nullptr, nullptr, nullptr, 512, 512, 1.f);
    k_mfma<0><<<dim3(4, 128, 1), 256, 0, stream>>>(S1, 0, 512, wtk, 0, 512, bk,
        S3, 0, nullptr, nullptr, nullptr, 512, 512, 1.f);
    k_mfma<3><<<dim3(4, 128, 1), 256, 0, stream>>>(S1, 0, 512, wtv, 0, 512, bv,
        S4, 0, nullptr, nullptr, nullptr, 512, 512, 1.f);
    // attention logits (NT): q_b . k_b^T * scale -> bf16 p_b
    k_mfma<0><<<dim3(16, 16, 8), 256, 0, stream>>>(S2, 2048LL * 512, 512, S3, 2048LL * 512, 512,
        nullptr, p_b, 4194304LL, nullptr, nullptr, nullptr, 2048, 512, invSqrtH);
    // softmax: bf16 logits -> f32 attn + normalized bf16 P in place
    k_softmax_b<<<16384, 256, 0, stream>>>(p_b, o_attn);
    // PV: P_b . v_t^T -> ctx_b (S1; gmem_b dead)
    k_mfma<0><<<dim3(4, 16, 8), 256, 0, stream>>>(p_b, 4194304LL, 2048, S4, 1048576LL, 2048,
        nullptr, S1, 1048576LL, nullptr, nullptr, nullptr, 512, 2048, 1.f);
    // free slots S3/S4 -> convert local/style
    k_cvt<<<4096, 256, 0, stream>>>(local_, S3, 8388608);
    k_cvt<<<4096, 256, 0, stream>>>(style, S4, 8388608);
    // Wo projection + prior epilogue (pd, pa, pa_b -> S2)
    k_mfma<2><<<dim3(4, 128, 1), 256, 0, stream>>>(S1, 0, 512, wto, 0, 512, bo,
        S2, 0, o_pd, o_pa, anchor, 512, 512, 1.f);
    // mix gate MLP (whid_b -> S1; ctx_b dead)
    k_cat<<<dim3(4, 128, 1), 256, 0, stream>>>(S0q, S2, S3, S4, 0, wtm1, bm1, S1);
    k_gate<<<16384, 64, 0, stream>>>(S1, Wm2, bm2, nullptr, o_mix, 1.0f, -0.25f);
    // slerp (bf16 inputs) -> candidate_absolute/delta f32 (+ca_b in-place S2)
    // NOTE: overwrites o_ca/o_cd which held p_b -- p_b dead after PV.
    k_slerp<<<16384, 64, 0, stream>>>(S2, S3, o_mix, anchor, o_ca, o_cd, S2);
    // variation gate MLP (src2 = anchor_b broadcast)
    k_cat<<<dim3(4, 128, 1), 256, 0, stream>>>(S0q, S2, anb, S4, 1, wtg1, bg1, S1);
    k_gate<<<16384, 64, 0, stream>>>(S1, Wg2, bg2, o_vl, o_vg, 1.0f, -1.0f);
}

// Round 7
// 459.371 us; speedup vs baseline: 1.1905x; 1.0474x over previous
//
#include <hip/hip_runtime.h>
#include <hip/hip_bf16.h>

typedef __hip_bfloat16 bf16;
typedef unsigned short u16;
typedef u16 u16x8 __attribute__((ext_vector_type(8)));
typedef u16 u16x4v __attribute__((ext_vector_type(4)));
typedef short bf16x8 __attribute__((ext_vector_type(8)));
typedef float f32x4 __attribute__((ext_vector_type(4)));

__device__ __forceinline__ float b2f(u16 u) {
    unsigned v = ((unsigned)u) << 16;
    float f; __builtin_memcpy(&f, &v, 4); return f;
}
__device__ __forceinline__ u16 f2u(float f) {
    bf16 h = __float2bfloat16(f);
    u16 u; __builtin_memcpy(&u, &h, 2); return u;
}
__device__ __forceinline__ float sigmoidf_(float x) { return 1.f / (1.f + expf(-x)); }
__device__ __forceinline__ void load8f(const float* __restrict__ p, float* x) {
    float4 a = *reinterpret_cast<const float4*>(p);
    float4 b = *reinterpret_cast<const float4*>(p + 4);
    x[0]=a.x; x[1]=a.y; x[2]=a.z; x[3]=a.w; x[4]=b.x; x[5]=b.y; x[6]=b.z; x[7]=b.w;
}

// async global->LDS, 16B per lane. LDS dest = wave-uniform base + lane*16.
__device__ __forceinline__ void gld16(const void* g, void* l) {
    typedef __attribute__((address_space(1))) const unsigned int GU;
    typedef __attribute__((address_space(3))) unsigned int LU;
    __builtin_amdgcn_global_load_lds((GU*)(unsigned long long)g,
                                     (LU*)(unsigned int)(unsigned long long)l, 16, 0, 0);
}

// ---------------------------------------------------------------------------
// m97-structure MFMA GEMM: C = A[m][k] . Bt[n][k]^T, batched over z.
// 128x128 tile, BK=32, 256 thr (4 waves 2x2), global_load_lds, linear LDS.
// 1D grid + XCD-aware decode:
//  SWZ 0 (batched): z = lin&7 (pins batch to XCD), t=lin>>3, x=t%GX, y=t/GX.
//  SWZ 1 (unbatched): chunked bijective: w=(lin&7)*(nwg/8)+(lin>>3),
//                     x=w%GX, y=w/GX  (nwg%8==0 guaranteed by launch).
// EPI 0: bf16 outb = acc*scale + bias, stride sO per z
// EPI 2: Wo: out1=pd=acc+bias; out2=pa=pd+anchor; outb=bf16(pa)   (z=0)
// ---------------------------------------------------------------------------
template<int EPI, int SWZ>
__global__ __launch_bounds__(256)
void k_mfma(const bf16* __restrict__ A, long long sA, int lda,
            const bf16* __restrict__ Bt, long long sB, int ldb,
            const float* __restrict__ bias,
            bf16* __restrict__ outb, long long sO,
            float* __restrict__ out1, float* __restrict__ out2,
            const float* __restrict__ anchor,
            int N, int K, float scale, int GX)
{
    __shared__ short As[4096];
    __shared__ short Bs[4096];
    const int tid = threadIdx.x;
    const int lin = blockIdx.x;
    int x, y, z;
    if constexpr (SWZ == 0) {
        z = lin & 7; const int t = lin >> 3; x = t % GX; y = t / GX;
    } else {
        const int q = (int)gridDim.x >> 3;
        const int wq = (lin & 7) * q + (lin >> 3);
        x = wq % GX; y = wq / GX; z = 0;
    }
    const int n0 = x * 128, m0 = y * 128;
    const bf16* Az = A + (long long)z * sA;
    const bf16* Bz = Bt + (long long)z * sB;
    const int lrow = tid >> 2;          // 0..63 staging row
    const int lcol = (tid & 3) * 8;     // k-chunk within 32
    const int lane = tid & 63, w = tid >> 6;
    const int wm = (w >> 1) * 64, wn = (w & 1) * 64;
    const int fr = lane & 15, fq = lane >> 4;
    char* AsW = (char*)As + w * 1024;   // wave-uniform LDS staging base
    char* BsW = (char*)Bs + w * 1024;

    f32x4 acc[4][4];
#pragma unroll
    for (int i = 0; i < 4; ++i)
#pragma unroll
        for (int j = 0; j < 4; ++j) acc[i][j] = f32x4{0.f, 0.f, 0.f, 0.f};

    for (int k0 = 0; k0 < K; k0 += 32) {
        const bf16* ga = Az + (long long)(m0 + lrow) * lda + (k0 + lcol);
        const bf16* gb = Bz + (long long)(n0 + lrow) * ldb + (k0 + lcol);
        gld16(ga, AsW);
        gld16(ga + 64LL * lda, AsW + 4096);
        gld16(gb, BsW);
        gld16(gb + 64LL * ldb, BsW + 4096);
        __syncthreads();

        bf16x8 af[4], bfr[4];
#pragma unroll
        for (int i = 0; i < 4; ++i)
            af[i] = *reinterpret_cast<const bf16x8*>(&As[(wm + i * 16 + fr) * 32 + fq * 8]);
#pragma unroll
        for (int j = 0; j < 4; ++j)
            bfr[j] = *reinterpret_cast<const bf16x8*>(&Bs[(wn + j * 16 + fr) * 32 + fq * 8]);
#pragma unroll
        for (int i = 0; i < 4; ++i)
#pragma unroll
            for (int j = 0; j < 4; ++j)
                acc[i][j] = __builtin_amdgcn_mfma_f32_16x16x32_bf16(af[i], bfr[j], acc[i][j], 0, 0, 0);
        __syncthreads();
    }

#pragma unroll
    for (int j = 0; j < 4; ++j) {
        const int col = n0 + wn + j * 16 + fr;
        const float bv = bias ? bias[col] : 0.f;
#pragma unroll
        for (int i = 0; i < 4; ++i) {
#pragma unroll
            for (int r = 0; r < 4; ++r) {
                const long long row = m0 + wm + i * 16 + fq * 4 + r;
                const float v = acc[i][j][r];
                if constexpr (EPI == 0) {
                    outb[(long long)z * sO + row * N + col] = __float2bfloat16(v * scale + bv);
                } else {
                    const float pd = v + bv;
                    const float pa = pd + anchor[(row >> 11) * 512 + col];
                    out1[row * N + col] = pd;
                    out2[row * N + col] = pa;
                    outb[row * N + col] = __float2bfloat16(pa);
                }
            }
        }
    }
}

// ---------------------------------------------------------------------------
// Softmax over bf16 logit rows of 2048 (one block/row, 256 thr):
// reads bf16 logits, writes f32 attn and normalized bf16 P in-place.
// ---------------------------------------------------------------------------
__global__ __launch_bounds__(256)
void k_softmax_b(bf16* __restrict__ Lb, float* __restrict__ attn)
{
    __shared__ float redm[4], reds[4];
    const long long row = blockIdx.x;
    bf16* lp = Lb + row * 2048;
    float* ap = attn + row * 2048;
    const int tid = threadIdx.x;

    u16x8 u = *reinterpret_cast<const u16x8*>(lp + tid * 8);
    float x[8];
    float mx = -1e30f;
#pragma unroll
    for (int j = 0; j < 8; ++j) { x[j] = b2f(u[j]); mx = fmaxf(mx, x[j]); }
#pragma unroll
    for (int off = 32; off; off >>= 1) mx = fmaxf(mx, __shfl_xor(mx, off));
    if ((tid & 63) == 0) redm[tid >> 6] = mx;
    __syncthreads();
    mx = fmaxf(fmaxf(redm[0], redm[1]), fmaxf(redm[2], redm[3]));

    float s = 0.f;
#pragma unroll
    for (int j = 0; j < 8; ++j) { x[j] = __expf(x[j] - mx); s += x[j]; }
#pragma unroll
    for (int off = 32; off; off >>= 1) s += __shfl_xor(s, off);
    if ((tid & 63) == 0) reds[tid >> 6] = s;
    __syncthreads();
    const float inv = 1.f / (reds[0] + reds[1] + reds[2] + reds[3]);

    u16x8 ob;
#pragma unroll
    for (int j = 0; j < 8; ++j) { x[j] *= inv; ob[j] = f2u(x[j]); }
    *reinterpret_cast<float4*>(ap + tid * 8)     = make_float4(x[0], x[1], x[2], x[3]);
    *reinterpret_cast<float4*>(ap + tid * 8 + 4) = make_float4(x[4], x[5], x[6], x[7]);
    *reinterpret_cast<u16x8*>(lp + tid * 8) = ob;
}

// ---------------------------------------------------------------------------
// Concat-gather MFMA GEMM (gate MLPs), chunked-XCD-swizzled 1D grid (nwg=512).
// A cols [0,2048) from 4 bf16 sources of 512 each (mode2=1: src2 = anchor_b
// broadcast). Bt bf16 [512][2048]. Epilogue: bf16 relu(acc+bias).
// ---------------------------------------------------------------------------
__global__ __launch_bounds__(256)
void k_cat(const bf16* __restrict__ s0b, const bf16* __restrict__ s1b,
           const bf16* __restrict__ s2b, const bf16* __restrict__ s3b,
           int mode2,
           const bf16* __restrict__ Bt, const float* __restrict__ bias,
           bf16* __restrict__ outb)
{
    __shared__ short As[4096];
    __shared__ short Bs[4096];
    const int tid = threadIdx.x;
    const int lin = blockIdx.x;
    const int q = (int)gridDim.x >> 3;
    const int wq = (lin & 7) * q + (lin >> 3);
    const int n0 = (wq & 3) * 128, m0 = (wq >> 2) * 128;
    const int lrow = tid >> 2;
    const int lcol = (tid & 3) * 8;
    const int lane = tid & 63, w = tid >> 6;
    const int wm = (w >> 1) * 64, wn = (w & 1) * 64;
    const int fr = lane & 15, fq = lane >> 4;
    char* AsW = (char*)As + w * 1024;
    char* BsW = (char*)Bs + w * 1024;

    f32x4 acc[4][4];
#pragma unroll
    for (int i = 0; i < 4; ++i)
#pragma unroll
        for (int j = 0; j < 4; ++j) acc[i][j] = f32x4{0.f, 0.f, 0.f, 0.f};

    for (int k0 = 0; k0 < 2048; k0 += 32) {
        const int si = k0 >> 9;
        const bf16* sp = si == 0 ? s0b : si == 1 ? s1b : si == 2 ? s2b : s3b;
        const int kloc = (k0 & 511) + lcol;
        const int r = m0 + lrow;
        long long ro0, ro1;
        if (si == 2 && mode2) { ro0 = (long long)(r >> 11) * 512; ro1 = ro0; }
        else                  { ro0 = (long long)r * 512; ro1 = ro0 + 64LL * 512; }
        gld16(sp + ro0 + kloc, AsW);
        gld16(sp + ro1 + kloc, AsW + 4096);
        const bf16* gb = Bt + (long long)(n0 + lrow) * 2048 + (k0 + lcol);
        gld16(gb, BsW);
        gld16(gb + 64LL * 2048, BsW + 4096);
        __syncthreads();

        bf16x8 af[4], bfr[4];
#pragma unroll
        for (int i = 0; i < 4; ++i)
            af[i] = *reinterpret_cast<const bf16x8*>(&As[(wm + i * 16 + fr) * 32 + fq * 8]);
#pragma unroll
        for (int j = 0; j < 4; ++j)
            bfr[j] = *reinterpret_cast<const bf16x8*>(&Bs[(wn + j * 16 + fr) * 32 + fq * 8]);
#pragma unroll
        for (int i = 0; i < 4; ++i)
#pragma unroll
            for (int j = 0; j < 4; ++j)
                acc[i][j] = __builtin_amdgcn_mfma_f32_16x16x32_bf16(af[i], bfr[j], acc[i][j], 0, 0, 0);
        __syncthreads();
    }

#pragma unroll
    for (int j = 0; j < 4; ++j) {
        const int col = n0 + wn + j * 16 + fr;
        const float bv = bias[col];
#pragma unroll
        for (int i = 0; i < 4; ++i)
#pragma unroll
            for (int r = 0; r < 4; ++r) {
                const long long row = m0 + wm + i * 16 + fq * 4 + r;
                outb[row * 512 + col] = __float2bfloat16(fmaxf(acc[i][j][r] + bv, 0.f));
            }
    }
}

// ---------------------------------------------------------------------------
// f32 -> bf16 elementwise convert, 8/thread. n multiple of 2048.
// ---------------------------------------------------------------------------
__global__ __launch_bounds__(256)
void k_cvt(const float* __restrict__ s, bf16* __restrict__ d, int n)
{
    long long i = ((long long)blockIdx.x * 256 + threadIdx.x) * 8;
    if (i >= n) return;
    float x[8]; load8f(s + i, x);
    u16x8 o;
#pragma unroll
    for (int j = 0; j < 8; ++j) o[j] = f2u(x[j]);
    *reinterpret_cast<u16x8*>(d + i) = o;
}

// ---------------------------------------------------------------------------
// Transposing convert: src f32 [R][C] -> dst bf16 [C][R]. 32x32 tiles.
// ---------------------------------------------------------------------------
__global__ __launch_bounds__(256)
void k_tr(const float* s0, bf16* d0, const float* s1, bf16* d1,
          const float* s2, bf16* d2, const float* s3, bf16* d3,
          int R, int C)
{
    __shared__ float t[32][33];
    const int zz = blockIdx.z;
    const float* s = zz == 0 ? s0 : zz == 1 ? s1 : zz == 2 ? s2 : s3;
    bf16* d = zz == 0 ? d0 : zz == 1 ? d1 : zz == 2 ? d2 : d3;
    const int c0 = blockIdx.x * 32, r0 = blockIdx.y * 32;
    const int tr = threadIdx.x >> 3, tc = (threadIdx.x & 7) * 4;
    float4 v = *reinterpret_cast<const float4*>(s + (long long)(r0 + tr) * C + c0 + tc);
    t[tr][tc] = v.x; t[tr][tc + 1] = v.y; t[tr][tc + 2] = v.z; t[tr][tc + 3] = v.w;
    __syncthreads();
    u16x4v o;
    o[0] = f2u(t[tc + 0][tr]); o[1] = f2u(t[tc + 1][tr]);
    o[2] = f2u(t[tc + 2][tr]); o[3] = f2u(t[tc + 3][tr]);
    *reinterpret_cast<u16x4v*>(d + (long long)(c0 + tr) * R + r0 + tc) = o;
}

// ---------------------------------------------------------------------------
// bf16 per-batch transpose: vb [B*2048][512] -> vt [B][512][2048].
// 32x32 tiles, coalesced both sides. grid (16, 64, 8).
// ---------------------------------------------------------------------------
__global__ __launch_bounds__(256)
void k_trb(const bf16* __restrict__ vb, bf16* __restrict__ vt)
{
    __shared__ u16 t[32][36];
    const int z = blockIdx.z;
    const int h0 = blockIdx.x * 32, s0 = blockIdx.y * 32;
    const int tr = threadIdx.x >> 3, tc = (threadIdx.x & 7) * 4;
    u16x4v a = *reinterpret_cast<const u16x4v*>(
        vb + ((long long)z * 2048 + s0 + tr) * 512 + h0 + tc);
    t[tr][tc] = a[0]; t[tr][tc + 1] = a[1]; t[tr][tc + 2] = a[2]; t[tr][tc + 3] = a[3];
    __syncthreads();
    u16x4v o;
    o[0] = t[tc + 0][tr]; o[1] = t[tc + 1][tr]; o[2] = t[tc + 2][tr]; o[3] = t[tc + 3][tr];
    *reinterpret_cast<u16x4v*>(
        vt + (long long)z * 1048576 + (long long)(h0 + tr) * 2048 + s0 + tc) = o;
}

// ---------------------------------------------------------------------------
// Gate GEMV over bf16 hidden: logit = hidden[row,:512] . w2 + b2. One wave/row.
// ---------------------------------------------------------------------------
__global__ __launch_bounds__(64)
void k_gate(const bf16* __restrict__ hidden, const float* __restrict__ w2,
            const float* __restrict__ b2,
            float* __restrict__ outLogit, float* __restrict__ outGate,
            float scl, float add)
{
    const long long row = blockIdx.x;
    const int lane = threadIdx.x;
    u16x8 u = *reinterpret_cast<const u16x8*>(hidden + row * 512 + lane * 8);
    float wv[8];
    load8f(w2 + lane * 8, wv);
    float s = 0.f;
#pragma unroll
    for (int j = 0; j < 8; ++j) s = fmaf(b2f(u[j]), wv[j], s);
#pragma unroll
    for (int off = 32; off; off >>= 1) s += __shfl_xor(s, off);
    if (lane == 0) {
        float logit = s + b2[0];
        if (outLogit) outLogit[row] = logit;
        outGate[row] = sigmoidf_(logit * scl + add);
    }
}

// ---------------------------------------------------------------------------
// Slerp: one wave per row. a=pa_b(bf16), b=local_b(bf16). Emits f32 cand/cdelta
// + bf16 cand (written in-place over pa_b slot).
// ---------------------------------------------------------------------------
__global__ __launch_bounds__(64)
void k_slerp(const bf16* __restrict__ priorb, const bf16* __restrict__ localb,
             const float* __restrict__ mixv, const float* __restrict__ anchor,
             float* __restrict__ cand, float* __restrict__ cdelta,
             bf16* __restrict__ candb)
{
    const int row = blockIdx.x;
    const int lane = threadIdx.x;
    const long long base = (long long)row * 512 + lane * 8;
    const long long abase = (long long)(row >> 11) * 512 + lane * 8;

    u16x8 ua = *reinterpret_cast<const u16x8*>(priorb + base);
    u16x8 ub = *reinterpret_cast<const u16x8*>(localb + base);
    float a[8], b[8];
    float sa = 0.f, sb = 0.f, sab = 0.f;
#pragma unroll
    for (int j = 0; j < 8; ++j) {
        a[j] = b2f(ua[j]); b[j] = b2f(ub[j]);
        sa = fmaf(a[j], a[j], sa); sb = fmaf(b[j], b[j], sb); sab = fmaf(a[j], b[j], sab);
    }
#pragma unroll
    for (int off = 1; off < 64; off <<= 1) {
        sa += __shfl_xor(sa, off); sb += __shfl_xor(sb, off); sab += __shfl_xor(sab, off);
    }
    const float eps = 1e-6f;
    float na = fmaxf(sqrtf(sa), eps), nb = fmaxf(sqrtf(sb), eps);
    float dot = sab / (na * nb);
    dot = fminf(fmaxf(dot, -1.f + eps), 1.f - eps);
    float omega = acosf(dot);
    float so = fmaxf(sinf(omega), eps);
    float t = mixv[row];
    t = fminf(fmaxf(t, 0.f), 1.f);
    float sca = sinf((1.f - t) * omega) / so;
    float scb = sinf(t * omega) / so;

    float an[8];
    load8f(anchor + abase, an);
    float c0[8], d0[8];
    u16x8 cb;
#pragma unroll
    for (int j = 0; j < 8; ++j) {
        c0[j] = sca * a[j] + scb * b[j];
        d0[j] = c0[j] - an[j];
        cb[j] = f2u(c0[j]);
    }
    *reinterpret_cast<float4*>(cand + base)       = make_float4(c0[0], c0[1], c0[2], c0[3]);
    *reinterpret_cast<float4*>(cand + base + 4)   = make_float4(c0[4], c0[5], c0[6], c0[7]);
    *reinterpret_cast<float4*>(cdelta + base)     = make_float4(d0[0], d0[1], d0[2], d0[3]);
    *reinterpret_cast<float4*>(cdelta + base + 4) = make_float4(d0[4], d0[5], d0[6], d0[7]);
    *reinterpret_cast<u16x8*>(candb + base) = cb;
}

// ---------------------------------------------------------------------------
extern "C" void kernel_launch(void* const* d_in, const int* in_sizes, int n_in,
                              void* d_out, int out_size, void* d_ws, size_t ws_size,
                              hipStream_t stream)
{
    const float* query  = (const float*)d_in[0];
    const float* anchor = (const float*)d_in[1];
    const float* gmem   = (const float*)d_in[2];
    const float* local_ = (const float*)d_in[3];
    const float* style  = (const float*)d_in[4];
    const float* Wq = (const float*)d_in[5];   const float* bq = (const float*)d_in[6];
    const float* Wk = (const float*)d_in[7];   const float* bk = (const float*)d_in[8];
    const float* Wv = (const float*)d_in[9];   const float* bv = (const float*)d_in[10];
    const float* Wo = (const float*)d_in[11];  const float* bo = (const float*)d_in[12];
    const float* Wm1 = (const float*)d_in[13]; const float* bm1 = (const float*)d_in[14];
    const float* Wm2 = (const float*)d_in[15]; const float* bm2 = (const float*)d_in[16];
    const float* Wg1 = (const float*)d_in[17]; const float* bg1 = (const float*)d_in[18];
    const float* Wg2 = (const float*)d_in[19]; const float* bg2 = (const float*)d_in[20];

    float* out = (float*)d_out;
    const long long SHE = 8388608LL;             // B*S*H elems
    float* o_attn = out;                         // [B,S,M]
    float* o_pd   = out + 33554432LL;            // prior_delta
    float* o_pa   = o_pd + SHE;                  // prior_absolute
    float* o_mix  = o_pa + SHE;                  // mix [16384]
    float* o_ca   = o_mix + 16384;               // candidate_absolute
    float* o_cd   = o_ca + SHE;                  // candidate_delta
    float* o_vl   = o_cd + SHE;                  // variation_logit
    float* o_vg   = o_vl + 16384;                // variation_gate

    // ws slots (bf16, 8.4M elems each, aggressively reused):
    bf16* S0q = (bf16*)d_ws;       // query_b (whole run)
    bf16* S1  = S0q + SHE;         // gmem_b -> ctx_b -> whid_b
    bf16* S2  = S1 + SHE;          // q_b -> pa_b -> ca_b
    bf16* S3  = S2 + SHE;          // k_b -> local_b
    bf16* S4  = S3 + SHE;          // v_t -> style_b
    bf16* wtq = S4 + SHE;          // transposed weights (bf16)
    bf16* wtk = wtq + 262144;
    bf16* wtv = wtk + 262144;
    bf16* wto = wtv + 262144;
    bf16* wtm1 = wto + 262144;     // [512][2048]
    bf16* wtg1 = wtm1 + 1048576;   // [512][2048]
    bf16* anb  = wtg1 + 1048576;   // anchor_b [8,512]
    bf16* p_b  = (bf16*)o_ca;      // bf16 logits->P in not-yet-written d_out (67 MB)
    bf16* v_b  = (bf16*)o_ca;      // row-major v staging (dead before QK^T writes p_b)

    const float invSqrtH = 0.04419417382415922f; // 1/sqrt(512)

    // prologue: bf16 conversions + weight transposes
    k_cvt<<<4096, 256, 0, stream>>>(query, S0q, 8388608);
    k_cvt<<<4096, 256, 0, stream>>>(gmem, S1, 8388608);
    k_cvt<<<2, 256, 0, stream>>>(anchor, anb, 4096);
    k_tr<<<dim3(16, 16, 4), 256, 0, stream>>>(Wq, wtq, Wk, wtk, Wv, wtv, Wo, wto, 512, 512);
    k_tr<<<dim3(16, 64, 2), 256, 0, stream>>>(Wm1, wtm1, Wg1, wtg1,
                                              nullptr, nullptr, nullptr, nullptr, 2048, 512);
    // q,k,v projections (chunked-XCD swizzle; v row-major then transposed)
    k_mfma<0, 1><<<512, 256, 0, stream>>>(S0q, 0, 512, wtq, 0, 512, bq,
        S2, 0, nullptr, nullptr, nullptr, 512, 512, 1.f, 4);
    k_mfma<0, 1><<<512, 256, 0, stream>>>(S1, 0, 512, wtk, 0, 512, bk,
        S3, 0, nullptr, nullptr, nullptr, 512, 512, 1.f, 4);
    k_mfma<0, 1><<<512, 256, 0, stream>>>(S1, 0, 512, wtv, 0, 512, bv,
        v_b, 0, nullptr, nullptr, nullptr, 512, 512, 1.f, 4);
    k_trb<<<dim3(16, 64, 8), 256, 0, stream>>>(v_b, S4);
    // attention logits (NT, batch-pinned-to-XCD): q_b . k_b^T * scale -> bf16 p_b
    k_mfma<0, 0><<<2048, 256, 0, stream>>>(S2, 2048LL * 512, 512, S3, 2048LL * 512, 512,
        nullptr, p_b, 4194304LL, nullptr, nullptr, nullptr, 2048, 512, invSqrtH, 16);
    // softmax: bf16 logits -> f32 attn + normalized bf16 P in place
    k_softmax_b<<<16384, 256, 0, stream>>>(p_b, o_attn);
    // PV (batch-pinned-to-XCD): P_b . v_t^T -> ctx_b (S1; gmem_b dead)
    k_mfma<0, 0><<<512, 256, 0, stream>>>(p_b, 4194304LL, 2048, S4, 1048576LL, 2048,
        nullptr, S1, 1048576LL, nullptr, nullptr, nullptr, 512, 2048, 1.f, 4);
    // free slots S3/S4 -> convert local/style
    k_cvt<<<4096, 256, 0, stream>>>(local_, S3, 8388608);
    k_cvt<<<4096, 256, 0, stream>>>(style, S4, 8388608);
    // Wo projection + prior epilogue (pd, pa, pa_b -> S2)
    k_mfma<2, 1><<<512, 256, 0, stream>>>(S1, 0, 512, wto, 0, 512, bo,
        S2, 0, o_pd, o_pa, anchor, 512, 512, 1.f, 4);
    // mix gate MLP (whid_b -> S1; ctx_b dead)
    k_cat<<<512, 256, 0, stream>>>(S0q, S2, S3, S4, 0, wtm1, bm1, S1);
    k_gate<<<16384, 64, 0, stream>>>(S1, Wm2, bm2, nullptr, o_mix, 1.0f, -0.25f);
    // slerp (bf16 inputs) -> candidate_absolute/delta f32 (+ca_b in-place S2)
    // NOTE: overwrites o_ca/o_cd which held p_b -- p_b dead after PV.
    k_slerp<<<16384, 64, 0, stream>>>(S2, S3, o_mix, anchor, o_ca, o_cd, S2);
    // variation gate MLP (src2 = anchor_b broadcast)
    k_cat<<<512, 256, 0, stream>>>(S0q, S2, anb, S4, 1, wtg1, bg1, S1);
    k_gate<<<16384, 64, 0, stream>>>(S1, Wg2, bg2, o_vl, o_vg, 1.0f, -1.0f);
}

// Round 8
// 430.764 us; speedup vs baseline: 1.2696x; 1.0664x over previous
//
#include <hip/hip_runtime.h>
#include <hip/hip_bf16.h>

typedef __hip_bfloat16 bf16;
typedef unsigned short u16;
typedef u16 u16x8 __attribute__((ext_vector_type(8)));
typedef u16 u16x4v __attribute__((ext_vector_type(4)));
typedef short bf16x8 __attribute__((ext_vector_type(8)));
typedef float f32x4 __attribute__((ext_vector_type(4)));

__device__ __forceinline__ float b2f(u16 u) {
    unsigned v = ((unsigned)u) << 16;
    float f; __builtin_memcpy(&f, &v, 4); return f;
}
__device__ __forceinline__ u16 f2u(float f) {
    bf16 h = __float2bfloat16(f);
    u16 u; __builtin_memcpy(&u, &h, 2); return u;
}
__device__ __forceinline__ float sigmoidf_(float x) { return 1.f / (1.f + expf(-x)); }
__device__ __forceinline__ void load8f(const float* __restrict__ p, float* x) {
    float4 a = *reinterpret_cast<const float4*>(p);
    float4 b = *reinterpret_cast<const float4*>(p + 4);
    x[0]=a.x; x[1]=a.y; x[2]=a.z; x[3]=a.w; x[4]=b.x; x[5]=b.y; x[6]=b.z; x[7]=b.w;
}

// async global->LDS, 16B per lane. LDS dest = wave-uniform base + lane*16.
__device__ __forceinline__ void gld16(const void* g, void* l) {
    typedef __attribute__((address_space(1))) const unsigned int GU;
    typedef __attribute__((address_space(3))) unsigned int LU;
    __builtin_amdgcn_global_load_lds((GU*)(unsigned long long)g,
                                     (LU*)(unsigned int)(unsigned long long)l, 16, 0, 0);
}

// ---------------------------------------------------------------------------
// m97-structure MFMA GEMM: C = A[m][k] . Bt[n][k]^T, batched over z.
// 128x128 tile, BK=32, 256 thr (4 waves 2x2), global_load_lds, linear LDS.
// 1D grid + XCD-aware decode (SWZ0: z=lin&7 batch pin; SWZ1: chunked bijective)
// EPI 0: bf16 outb = acc*scale + bias
// EPI 1: KV dual: col<512 -> outb (k_b) + bias; col>=512 -> outb2 (v_b) + bias2
// EPI 2: Wo: out1=pd=acc+bias; out2=pa=pd+anchor; outb=bf16(pa)
// ---------------------------------------------------------------------------
template<int EPI, int SWZ>
__global__ __launch_bounds__(256)
void k_mfma(const bf16* __restrict__ A, long long sA, int lda,
            const bf16* __restrict__ Bt, long long sB, int ldb,
            const float* __restrict__ bias, const float* __restrict__ bias2,
            bf16* __restrict__ outb, bf16* __restrict__ outb2, long long sO,
            float* __restrict__ out1, float* __restrict__ out2,
            const float* __restrict__ anchor,
            int N, int K, float scale, int GX)
{
    __shared__ short As[4096];
    __shared__ short Bs[4096];
    const int tid = threadIdx.x;
    const int lin = blockIdx.x;
    int x, y, z;
    if constexpr (SWZ == 0) {
        z = lin & 7; const int t = lin >> 3; x = t % GX; y = t / GX;
    } else {
        const int q = (int)gridDim.x >> 3;
        const int wq = (lin & 7) * q + (lin >> 3);
        x = wq % GX; y = wq / GX; z = 0;
    }
    const int n0 = x * 128, m0 = y * 128;
    const bf16* Az = A + (long long)z * sA;
    const bf16* Bz = Bt + (long long)z * sB;
    const int lrow = tid >> 2;
    const int lcol = (tid & 3) * 8;
    const int lane = tid & 63, w = tid >> 6;
    const int wm = (w >> 1) * 64, wn = (w & 1) * 64;
    const int fr = lane & 15, fq = lane >> 4;
    char* AsW = (char*)As + w * 1024;
    char* BsW = (char*)Bs + w * 1024;

    f32x4 acc[4][4];
#pragma unroll
    for (int i = 0; i < 4; ++i)
#pragma unroll
        for (int j = 0; j < 4; ++j) acc[i][j] = f32x4{0.f, 0.f, 0.f, 0.f};

    for (int k0 = 0; k0 < K; k0 += 32) {
        const bf16* ga = Az + (long long)(m0 + lrow) * lda + (k0 + lcol);
        const bf16* gb = Bz + (long long)(n0 + lrow) * ldb + (k0 + lcol);
        gld16(ga, AsW);
        gld16(ga + 64LL * lda, AsW + 4096);
        gld16(gb, BsW);
        gld16(gb + 64LL * ldb, BsW + 4096);
        __syncthreads();

        bf16x8 af[4], bfr[4];
#pragma unroll
        for (int i = 0; i < 4; ++i)
            af[i] = *reinterpret_cast<const bf16x8*>(&As[(wm + i * 16 + fr) * 32 + fq * 8]);
#pragma unroll
        for (int j = 0; j < 4; ++j)
            bfr[j] = *reinterpret_cast<const bf16x8*>(&Bs[(wn + j * 16 + fr) * 32 + fq * 8]);
#pragma unroll
        for (int i = 0; i < 4; ++i)
#pragma unroll
            for (int j = 0; j < 4; ++j)
                acc[i][j] = __builtin_amdgcn_mfma_f32_16x16x32_bf16(af[i], bfr[j], acc[i][j], 0, 0, 0);
        __syncthreads();
    }

#pragma unroll
    for (int j = 0; j < 4; ++j) {
        const int col = n0 + wn + j * 16 + fr;
        float bv;
        if constexpr (EPI == 1) bv = (col < 512) ? bias[col] : bias2[col - 512];
        else                    bv = bias ? bias[col] : 0.f;
#pragma unroll
        for (int i = 0; i < 4; ++i) {
#pragma unroll
            for (int r = 0; r < 4; ++r) {
                const long long row = m0 + wm + i * 16 + fq * 4 + r;
                const float v = acc[i][j][r];
                if constexpr (EPI == 0) {
                    outb[(long long)z * sO + row * N + col] = __float2bfloat16(v * scale + bv);
                } else if constexpr (EPI == 1) {
                    if (col < 512) outb[row * 512 + col] = __float2bfloat16(v + bv);
                    else           outb2[row * 512 + (col - 512)] = __float2bfloat16(v + bv);
                } else {
                    const float pd = v + bv;
                    const float pa = pd + anchor[(row >> 11) * 512 + col];
                    out1[row * N + col] = pd;
                    out2[row * N + col] = pa;
                    outb[row * N + col] = __float2bfloat16(pa);
                }
            }
        }
    }
}

// ---------------------------------------------------------------------------
// Softmax over bf16 logit rows of 2048 (one block/row, 256 thr):
// reads bf16 logits, writes f32 attn and normalized bf16 P in-place.
// ---------------------------------------------------------------------------
__global__ __launch_bounds__(256)
void k_softmax_b(bf16* __restrict__ Lb, float* __restrict__ attn)
{
    __shared__ float redm[4], reds[4];
    const long long row = blockIdx.x;
    bf16* lp = Lb + row * 2048;
    float* ap = attn + row * 2048;
    const int tid = threadIdx.x;

    u16x8 u = *reinterpret_cast<const u16x8*>(lp + tid * 8);
    float x[8];
    float mx = -1e30f;
#pragma unroll
    for (int j = 0; j < 8; ++j) { x[j] = b2f(u[j]); mx = fmaxf(mx, x[j]); }
#pragma unroll
    for (int off = 32; off; off >>= 1) mx = fmaxf(mx, __shfl_xor(mx, off));
    if ((tid & 63) == 0) redm[tid >> 6] = mx;
    __syncthreads();
    mx = fmaxf(fmaxf(redm[0], redm[1]), fmaxf(redm[2], redm[3]));

    float s = 0.f;
#pragma unroll
    for (int j = 0; j < 8; ++j) { x[j] = __expf(x[j] - mx); s += x[j]; }
#pragma unroll
    for (int off = 32; off; off >>= 1) s += __shfl_xor(s, off);
    if ((tid & 63) == 0) reds[tid >> 6] = s;
    __syncthreads();
    const float inv = 1.f / (reds[0] + reds[1] + reds[2] + reds[3]);

    u16x8 ob;
#pragma unroll
    for (int j = 0; j < 8; ++j) { x[j] *= inv; ob[j] = f2u(x[j]); }
    *reinterpret_cast<float4*>(ap + tid * 8)     = make_float4(x[0], x[1], x[2], x[3]);
    *reinterpret_cast<float4*>(ap + tid * 8 + 4) = make_float4(x[4], x[5], x[6], x[7]);
    *reinterpret_cast<u16x8*>(lp + tid * 8) = ob;
}

// ---------------------------------------------------------------------------
// Concat-gather MFMA GEMM + fused hidden GEMV partial (gate MLPs).
// A cols [0,2048) from 4 bf16 sources of 512 (mode2=1: src2 = anchor_b
// broadcast). Bt bf16 [512][2048]. Per block: partial_row = sum over its 128
// cols of relu(acc+b1[col]) * w2[col]  -> part[row*4 + xtile].  No whid.
// ---------------------------------------------------------------------------
__global__ __launch_bounds__(256)
void k_cat(const bf16* __restrict__ s0b, const bf16* __restrict__ s1b,
           const bf16* __restrict__ s2b, const bf16* __restrict__ s3b,
           int mode2,
           const bf16* __restrict__ Bt, const float* __restrict__ bias,
           const float* __restrict__ w2, float* __restrict__ part)
{
    __shared__ short As[4096];
    __shared__ short Bs[4096];
    __shared__ float pl[128][2];
    const int tid = threadIdx.x;
    const int lin = blockIdx.x;
    const int q = (int)gridDim.x >> 3;
    const int wq = (lin & 7) * q + (lin >> 3);
    const int xt = wq & 3;
    const int n0 = xt * 128, m0 = (wq >> 2) * 128;
    const int lrow = tid >> 2;
    const int lcol = (tid & 3) * 8;
    const int lane = tid & 63, w = tid >> 6;
    const int wm = (w >> 1) * 64, wn = (w & 1) * 64;
    const int fr = lane & 15, fq = lane >> 4;
    char* AsW = (char*)As + w * 1024;
    char* BsW = (char*)Bs + w * 1024;

    f32x4 acc[4][4];
#pragma unroll
    for (int i = 0; i < 4; ++i)
#pragma unroll
        for (int j = 0; j < 4; ++j) acc[i][j] = f32x4{0.f, 0.f, 0.f, 0.f};

    for (int k0 = 0; k0 < 2048; k0 += 32) {
        const int si = k0 >> 9;
        const bf16* sp = si == 0 ? s0b : si == 1 ? s1b : si == 2 ? s2b : s3b;
        const int kloc = (k0 & 511) + lcol;
        const int r = m0 + lrow;
        long long ro0, ro1;
        if (si == 2 && mode2) { ro0 = (long long)(r >> 11) * 512; ro1 = ro0; }
        else                  { ro0 = (long long)r * 512; ro1 = ro0 + 64LL * 512; }
        gld16(sp + ro0 + kloc, AsW);
        gld16(sp + ro1 + kloc, AsW + 4096);
        const bf16* gb = Bt + (long long)(n0 + lrow) * 2048 + (k0 + lcol);
        gld16(gb, BsW);
        gld16(gb + 64LL * 2048, BsW + 4096);
        __syncthreads();

        bf16x8 af[4], bfr[4];
#pragma unroll
        for (int i = 0; i < 4; ++i)
            af[i] = *reinterpret_cast<const bf16x8*>(&As[(wm + i * 16 + fr) * 32 + fq * 8]);
#pragma unroll
        for (int j = 0; j < 4; ++j)
            bfr[j] = *reinterpret_cast<const bf16x8*>(&Bs[(wn + j * 16 + fr) * 32 + fq * 8]);
#pragma unroll
        for (int i = 0; i < 4; ++i)
#pragma unroll
            for (int j = 0; j < 4; ++j)
                acc[i][j] = __builtin_amdgcn_mfma_f32_16x16x32_bf16(af[i], bfr[j], acc[i][j], 0, 0, 0);
        __syncthreads();
    }

    // fused second-layer partial: relu(acc+b1)*w2, summed over block's cols
    float pt[4][4];
#pragma unroll
    for (int i = 0; i < 4; ++i)
#pragma unroll
        for (int r = 0; r < 4; ++r) pt[i][r] = 0.f;
#pragma unroll
    for (int j = 0; j < 4; ++j) {
        const int col = n0 + wn + j * 16 + fr;
        const float bv = bias[col];
        const float wv = w2[col];
#pragma unroll
        for (int i = 0; i < 4; ++i)
#pragma unroll
            for (int r = 0; r < 4; ++r)
                pt[i][r] = fmaf(fmaxf(acc[i][j][r] + bv, 0.f), wv, pt[i][r]);
    }
#pragma unroll
    for (int off = 1; off < 16; off <<= 1)
#pragma unroll
        for (int i = 0; i < 4; ++i)
#pragma unroll
            for (int r = 0; r < 4; ++r)
                pt[i][r] += __shfl_xor(pt[i][r], off);
    if (fr == 0)
#pragma unroll
        for (int i = 0; i < 4; ++i)
#pragma unroll
            for (int r = 0; r < 4; ++r)
                pl[wm + i * 16 + fq * 4 + r][wn >> 6] = pt[i][r];
    __syncthreads();
    if (tid < 128)
        part[(long long)(m0 + tid) * 4 + xt] = pl[tid][0] + pl[tid][1];
}

// ---------------------------------------------------------------------------
// Fat prologue: query/gmem/anchor f32->bf16 + 6 weight transposes (f32->bf16^T)
// grid = 11266 blocks x 256.
// ---------------------------------------------------------------------------
__global__ __launch_bounds__(256)
void k_prologue(const float* __restrict__ query, bf16* __restrict__ qb,
                const float* __restrict__ gmem, bf16* __restrict__ gb,
                const float* __restrict__ anchor, bf16* __restrict__ anb,
                const float* Wq, bf16* wtq, const float* Wk, bf16* wtk,
                const float* Wv, bf16* wtv, const float* Wo, bf16* wto,
                const float* Wm1, bf16* wtm1, const float* Wg1, bf16* wtg1)
{
    __shared__ float tls[32][33];
    const int b = blockIdx.x;
    const int tid = threadIdx.x;
    if (b < 8192) {
        const float* s = (b < 4096) ? query : gmem;
        bf16* d = (b < 4096) ? qb : gb;
        const long long i = ((long long)(b & 4095) * 256 + tid) * 8;
        float x[8]; load8f(s + i, x);
        u16x8 o;
#pragma unroll
        for (int j = 0; j < 8; ++j) o[j] = f2u(x[j]);
        *reinterpret_cast<u16x8*>(d + i) = o;
        return;
    }
    if (b < 8194) {
        const int i = ((b - 8192) * 256 + tid) * 8;
        if (i < 4096) {
            float x[8]; load8f(anchor + i, x);
            u16x8 o;
#pragma unroll
            for (int j = 0; j < 8; ++j) o[j] = f2u(x[j]);
            *reinterpret_cast<u16x8*>(anb + i) = o;
        }
        return;
    }
    const float* s; bf16* d; int R, C, ti;
    if (b < 9218) {
        const int bi = b - 8194; const int zz = bi >> 8; ti = bi & 255;
        s = zz == 0 ? Wq : zz == 1 ? Wk : zz == 2 ? Wv : Wo;
        d = zz == 0 ? wtq : zz == 1 ? wtk : zz == 2 ? wtv : wto;
        R = 512; C = 512;
    } else {
        const int bi = b - 9218; const int zz = bi >> 10; ti = bi & 1023;
        s = zz ? Wg1 : Wm1; d = zz ? wtg1 : wtm1;
        R = 2048; C = 512;
    }
    const int c0 = (ti & 15) * 32, r0 = (ti >> 4) * 32;
    const int tr = tid >> 3, tc = (tid & 7) * 4;
    float4 v = *reinterpret_cast<const float4*>(s + (long long)(r0 + tr) * C + c0 + tc);
    tls[tr][tc] = v.x; tls[tr][tc + 1] = v.y; tls[tr][tc + 2] = v.z; tls[tr][tc + 3] = v.w;
    __syncthreads();
    u16x4v o;
    o[0] = f2u(tls[tc + 0][tr]); o[1] = f2u(tls[tc + 1][tr]);
    o[2] = f2u(tls[tc + 2][tr]); o[3] = f2u(tls[tc + 3][tr]);
    *reinterpret_cast<u16x4v*>(d + (long long)(c0 + tr) * R + r0 + tc) = o;
}

// ---------------------------------------------------------------------------
// merged local+style f32->bf16. grid 8192.
// ---------------------------------------------------------------------------
__global__ __launch_bounds__(256)
void k_cvt2(const float* __restrict__ s0, bf16* __restrict__ d0,
            const float* __restrict__ s1, bf16* __restrict__ d1)
{
    const int b = blockIdx.x;
    const float* s = (b < 4096) ? s0 : s1;
    bf16* d = (b < 4096) ? d0 : d1;
    const long long i = ((long long)(b & 4095) * 256 + threadIdx.x) * 8;
    float x[8]; load8f(s + i, x);
    u16x8 o;
#pragma unroll
    for (int j = 0; j < 8; ++j) o[j] = f2u(x[j]);
    *reinterpret_cast<u16x8*>(d + i) = o;
}

// ---------------------------------------------------------------------------
// bf16 per-batch transpose: vb [B*2048][512] -> vt [B][512][2048].
// ---------------------------------------------------------------------------
__global__ __launch_bounds__(256)
void k_trb(const bf16* __restrict__ vb, bf16* __restrict__ vt)
{
    __shared__ u16 t[32][36];
    const int z = blockIdx.z;
    const int h0 = blockIdx.x * 32, s0 = blockIdx.y * 32;
    const int tr = threadIdx.x >> 3, tc = (threadIdx.x & 7) * 4;
    u16x4v a = *reinterpret_cast<const u16x4v*>(
        vb + ((long long)z * 2048 + s0 + tr) * 512 + h0 + tc);
    t[tr][tc] = a[0]; t[tr][tc + 1] = a[1]; t[tr][tc + 2] = a[2]; t[tr][tc + 3] = a[3];
    __syncthreads();
    u16x4v o;
    o[0] = t[tc + 0][tr]; o[1] = t[tc + 1][tr]; o[2] = t[tc + 2][tr]; o[3] = t[tc + 3][tr];
    *reinterpret_cast<u16x4v*>(
        vt + (long long)z * 1048576 + (long long)(h0 + tr) * 2048 + s0 + tc) = o;
}

// ---------------------------------------------------------------------------
// mix finisher + slerp, one wave per row: logit = sum(part[row])+b2;
// mix = sigmoid(logit-0.25); slerp(prior,local,mix) -> cand/cdelta/candb.
// ---------------------------------------------------------------------------
__global__ __launch_bounds__(64)
void k_gate_slerp(const float* __restrict__ part, const float* __restrict__ b2,
                  const bf16* __restrict__ priorb, const bf16* __restrict__ localb,
                  const float* __restrict__ anchor,
                  float* __restrict__ o_mix,
                  float* __restrict__ cand, float* __restrict__ cdelta,
                  bf16* __restrict__ candb)
{
    const int row = blockIdx.x;
    const int lane = threadIdx.x;
    float v = (lane < 4) ? part[(long long)row * 4 + lane] : 0.f;
    v += __shfl_xor(v, 1);
    v += __shfl_xor(v, 2);
    const float logit = __shfl(v, 0) + b2[0];
    float t = sigmoidf_(logit - 0.25f);
    if (lane == 0) o_mix[row] = t;
    t = fminf(fmaxf(t, 0.f), 1.f);

    const long long base = (long long)row * 512 + lane * 8;
    const long long abase = (long long)(row >> 11) * 512 + lane * 8;
    u16x8 ua = *reinterpret_cast<const u16x8*>(priorb + base);
    u16x8 ub = *reinterpret_cast<const u16x8*>(localb + base);
    float a[8], b[8];
    float sa = 0.f, sb = 0.f, sab = 0.f;
#pragma unroll
    for (int j = 0; j < 8; ++j) {
        a[j] = b2f(ua[j]); b[j] = b2f(ub[j]);
        sa = fmaf(a[j], a[j], sa); sb = fmaf(b[j], b[j], sb); sab = fmaf(a[j], b[j], sab);
    }
#pragma unroll
    for (int off = 1; off < 64; off <<= 1) {
        sa += __shfl_xor(sa, off); sb += __shfl_xor(sb, off); sab += __shfl_xor(sab, off);
    }
    const float eps = 1e-6f;
    float na = fmaxf(sqrtf(sa), eps), nb = fmaxf(sqrtf(sb), eps);
    float dot = sab / (na * nb);
    dot = fminf(fmaxf(dot, -1.f + eps), 1.f - eps);
    float omega = acosf(dot);
    float so = fmaxf(sinf(omega), eps);
    float sca = sinf((1.f - t) * omega) / so;
    float scb = sinf(t * omega) / so;

    float an[8];
    load8f(anchor + abase, an);
    float c0[8], d0[8];
    u16x8 cb;
#pragma unroll
    for (int j = 0; j < 8; ++j) {
        c0[j] = sca * a[j] + scb * b[j];
        d0[j] = c0[j] - an[j];
        cb[j] = f2u(c0[j]);
    }
    *reinterpret_cast<float4*>(cand + base)       = make_float4(c0[0], c0[1], c0[2], c0[3]);
    *reinterpret_cast<float4*>(cand + base + 4)   = make_float4(c0[4], c0[5], c0[6], c0[7]);
    *reinterpret_cast<float4*>(cdelta + base)     = make_float4(d0[0], d0[1], d0[2], d0[3]);
    *reinterpret_cast<float4*>(cdelta + base + 4) = make_float4(d0[4], d0[5], d0[6], d0[7]);
    *reinterpret_cast<u16x8*>(candb + base) = cb;
}

// ---------------------------------------------------------------------------
// variation finisher: thread per row. logit -> o_vl, sigmoid(logit-1) -> o_vg.
// ---------------------------------------------------------------------------
__global__ __launch_bounds__(256)
void k_gate_var(const float* __restrict__ part, const float* __restrict__ b2,
                float* __restrict__ o_vl, float* __restrict__ o_vg)
{
    const long long row = (long long)blockIdx.x * 256 + threadIdx.x;
    float4 p = *reinterpret_cast<const float4*>(part + row * 4);
    const float logit = (p.x + p.y) + (p.z + p.w) + b2[0];
    o_vl[row] = logit;
    o_vg[row] = sigmoidf_(logit - 1.0f);
}

// ---------------------------------------------------------------------------
extern "C" void kernel_launch(void* const* d_in, const int* in_sizes, int n_in,
                              void* d_out, int out_size, void* d_ws, size_t ws_size,
                              hipStream_t stream)
{
    const float* query  = (const float*)d_in[0];
    const float* anchor = (const float*)d_in[1];
    const float* gmem   = (const float*)d_in[2];
    const float* local_ = (const float*)d_in[3];
    const float* style  = (const float*)d_in[4];
    const float* Wq = (const float*)d_in[5];   const float* bq = (const float*)d_in[6];
    const float* Wk = (const float*)d_in[7];   const float* bk = (const float*)d_in[8];
    const float* Wv = (const float*)d_in[9];   const float* bv = (const float*)d_in[10];
    const float* Wo = (const float*)d_in[11];  const float* bo = (const float*)d_in[12];
    const float* Wm1 = (const float*)d_in[13]; const float* bm1 = (const float*)d_in[14];
    const float* Wm2 = (const float*)d_in[15]; const float* bm2 = (const float*)d_in[16];
    const float* Wg1 = (const float*)d_in[17]; const float* bg1 = (const float*)d_in[18];
    const float* Wg2 = (const float*)d_in[19]; const float* bg2 = (const float*)d_in[20];

    float* out = (float*)d_out;
    const long long SHE = 8388608LL;             // B*S*H elems
    float* o_attn = out;                         // [B,S,M]
    float* o_pd   = out + 33554432LL;            // prior_delta
    float* o_pa   = o_pd + SHE;                  // prior_absolute
    float* o_mix  = o_pa + SHE;                  // mix [16384]
    float* o_ca   = o_mix + 16384;               // candidate_absolute
    float* o_cd   = o_ca + SHE;                  // candidate_delta
    float* o_vl   = o_cd + SHE;                  // variation_logit
    float* o_vg   = o_vl + 16384;                // variation_gate

    // ws slots (bf16, 8.4M elems each, aggressively reused):
    bf16* S0q = (bf16*)d_ws;       // query_b (whole run)
    bf16* S1  = S0q + SHE;         // gmem_b -> ctx_b
    bf16* S2  = S1 + SHE;          // q_b -> pa_b -> ca_b
    bf16* S3  = S2 + SHE;          // k_b -> local_b
    bf16* S4  = S3 + SHE;          // v_t -> style_b
    bf16* wtq = S4 + SHE;          // transposed weights (bf16)
    bf16* wtk = wtq + 262144;      // wtk,wtv contiguous => KV merged B [1024][512]
    bf16* wtv = wtk + 262144;
    bf16* wto = wtv + 262144;
    bf16* wtm1 = wto + 262144;     // [512][2048]
    bf16* wtg1 = wtm1 + 1048576;   // [512][2048]
    bf16* anb  = wtg1 + 1048576;   // anchor_b [8,512]
    float* part_m = (float*)(anb + 4096);  // [16384][4]
    float* part_v = part_m + 65536;        // [16384][4]
    bf16* p_b  = (bf16*)o_ca;      // bf16 logits->P in not-yet-written d_out (67 MB)
    bf16* v_b  = (bf16*)o_ca;      // row-major v staging (dead before QK^T writes p_b)

    const float invSqrtH = 0.04419417382415922f; // 1/sqrt(512)

    // fat prologue: all conversions + weight transposes in one launch
    k_prologue<<<11266, 256, 0, stream>>>(query, S0q, gmem, S1, anchor, anb,
        Wq, wtq, Wk, wtk, Wv, wtv, Wo, wto, Wm1, wtm1, Wg1, wtg1);
    // q projection
    k_mfma<0, 1><<<512, 256, 0, stream>>>(S0q, 0, 512, wtq, 0, 512, bq, nullptr,
        S2, nullptr, 0, nullptr, nullptr, nullptr, 512, 512, 1.f, 4);
    // merged K+V projection (shared A = gmem_b), N=1024
    k_mfma<1, 1><<<1024, 256, 0, stream>>>(S1, 0, 512, wtk, 0, 512, bk, bv,
        S3, v_b, 0, nullptr, nullptr, nullptr, 1024, 512, 1.f, 8);
    k_trb<<<dim3(16, 64, 8), 256, 0, stream>>>(v_b, S4);
    // attention logits (NT, batch-pinned-to-XCD): q_b . k_b^T * scale -> bf16 p_b
    k_mfma<0, 0><<<2048, 256, 0, stream>>>(S2, 2048LL * 512, 512, S3, 2048LL * 512, 512,
        nullptr, nullptr, p_b, nullptr, 4194304LL, nullptr, nullptr, nullptr,
        2048, 512, invSqrtH, 16);
    // softmax: bf16 logits -> f32 attn + normalized bf16 P in place
    k_softmax_b<<<16384, 256, 0, stream>>>(p_b, o_attn);
    // PV (batch-pinned-to-XCD): P_b . v_t^T -> ctx_b (S1; gmem_b dead)
    k_mfma<0, 0><<<512, 256, 0, stream>>>(p_b, 4194304LL, 2048, S4, 1048576LL, 2048,
        nullptr, nullptr, S1, nullptr, 1048576LL, nullptr, nullptr, nullptr,
        512, 2048, 1.f, 4);
    // free slots S3/S4 -> convert local/style (one launch)
    k_cvt2<<<8192, 256, 0, stream>>>(local_, S3, style, S4);
    // Wo projection + prior epilogue (pd, pa, pa_b -> S2)
    k_mfma<2, 1><<<512, 256, 0, stream>>>(S1, 0, 512, wto, 0, 512, bo, nullptr,
        S2, nullptr, 0, o_pd, o_pa, anchor, 512, 512, 1.f, 4);
    // mix gate MLP -> per-block partials (no whid)
    k_cat<<<512, 256, 0, stream>>>(S0q, S2, S3, S4, 0, wtm1, bm1, Wm2, part_m);
    // mix finisher + slerp (reads pa_b, writes ca_b in place over S2)
    k_gate_slerp<<<16384, 64, 0, stream>>>(part_m, bm2, S2, S3, anchor,
        o_mix, o_ca, o_cd, S2);
    // variation gate MLP (src2 = anchor_b broadcast)
    k_cat<<<512, 256, 0, stream>>>(S0q, S2, anb, S4, 1, wtg1, bg1, Wg2, part_v);
    k_gate_var<<<64, 256, 0, stream>>>(part_v, bg2, o_vl, o_vg);
}

// Round 10
// 396.021 us; speedup vs baseline: 1.3810x; 1.0877x over previous
//
#include <hip/hip_runtime.h>
#include <hip/hip_bf16.h>

typedef __hip_bfloat16 bf16;
typedef unsigned short u16;
typedef u16 u16x8 __attribute__((ext_vector_type(8)));
typedef u16 u16x4v __attribute__((ext_vector_type(4)));
typedef short bf16x8 __attribute__((ext_vector_type(8)));
typedef float f32x4 __attribute__((ext_vector_type(4)));

__device__ __forceinline__ float b2f(u16 u) {
    unsigned v = ((unsigned)u) << 16;
    float f; __builtin_memcpy(&f, &v, 4); return f;
}
__device__ __forceinline__ u16 f2u(float f) {
    bf16 h = __float2bfloat16(f);
    u16 u; __builtin_memcpy(&u, &h, 2); return u;
}
__device__ __forceinline__ float sigmoidf_(float x) { return 1.f / (1.f + expf(-x)); }
__device__ __forceinline__ void load8f(const float* __restrict__ p, float* x) {
    float4 a = *reinterpret_cast<const float4*>(p);
    float4 b = *reinterpret_cast<const float4*>(p + 4);
    x[0]=a.x; x[1]=a.y; x[2]=a.z; x[3]=a.w; x[4]=b.x; x[5]=b.y; x[6]=b.z; x[7]=b.w;
}
// nt store of 4 floats via native clang vector (HIP float4 is a struct and
// is rejected by __builtin_nontemporal_store).
__device__ __forceinline__ void nt_store4(float* p, float a, float b, float c, float d) {
    f32x4 v = {a, b, c, d};
    __builtin_nontemporal_store(v, reinterpret_cast<f32x4*>(p));
}
__device__ __forceinline__ void nt_store1(float* p, float a) {
    __builtin_nontemporal_store(a, p);
}

// async global->LDS, 16B per lane. LDS dest = wave-uniform base + lane*16.
__device__ __forceinline__ void gld16(const void* g, void* l) {
    typedef __attribute__((address_space(1))) const unsigned int GU;
    typedef __attribute__((address_space(3))) unsigned int LU;
    __builtin_amdgcn_global_load_lds((GU*)(unsigned long long)g,
                                     (LU*)(unsigned int)(unsigned long long)l, 16, 0, 0);
}

// ---------------------------------------------------------------------------
// m97-structure MFMA GEMM core: C = A[m][k] . Bt[n][k]^T, batched over z.
// 128x128 tile, BK=32, 256 thr (4 waves 2x2), global_load_lds, linear LDS.
// SWZ0 (batched): z=lin&7 (batch->XCD pin), t=lin>>3, x=t%GX, y=t/GX.
// SWZ1 (unbatched): chunked bijective over nwg (nwg%8==0).
// EPI 0: bf16 outb = acc*scale + bias
// EPI 1: KV dual: col<512 -> outb (k_b); col>=512 -> outb2 (v_b)
// EPI 2: Wo: out1=pd (nt); out2=pa (nt); outb=bf16(pa)
// ---------------------------------------------------------------------------
template<int EPI, int SWZ>
__device__ __forceinline__ void mfma_core(
    int lin, int nwg, short* As, short* Bs,
    const bf16* A, long long sA, int lda,
    const bf16* Bt, long long sB, int ldb,
    const float* bias, const float* bias2,
    bf16* outb, bf16* outb2, long long sO,
    float* out1, float* out2, const float* anchor,
    int N, int K, float scale, int GX)
{
    const int tid = threadIdx.x;
    int x, y, z;
    if constexpr (SWZ == 0) {
        z = lin & 7; const int t = lin >> 3; x = t % GX; y = t / GX;
    } else {
        const int q = nwg >> 3;
        const int wq = (lin & 7) * q + (lin >> 3);
        x = wq % GX; y = wq / GX; z = 0;
    }
    const int n0 = x * 128, m0 = y * 128;
    const bf16* Az = A + (long long)z * sA;
    const bf16* Bz = Bt + (long long)z * sB;
    const int lrow = tid >> 2;
    const int lcol = (tid & 3) * 8;
    const int lane = tid & 63, w = tid >> 6;
    const int wm = (w >> 1) * 64, wn = (w & 1) * 64;
    const int fr = lane & 15, fq = lane >> 4;
    char* AsW = (char*)As + w * 1024;
    char* BsW = (char*)Bs + w * 1024;

    f32x4 acc[4][4];
#pragma unroll
    for (int i = 0; i < 4; ++i)
#pragma unroll
        for (int j = 0; j < 4; ++j) acc[i][j] = f32x4{0.f, 0.f, 0.f, 0.f};

    for (int k0 = 0; k0 < K; k0 += 32) {
        const bf16* ga = Az + (long long)(m0 + lrow) * lda + (k0 + lcol);
        const bf16* gb = Bz + (long long)(n0 + lrow) * ldb + (k0 + lcol);
        gld16(ga, AsW);
        gld16(ga + 64LL * lda, AsW + 4096);
        gld16(gb, BsW);
        gld16(gb + 64LL * ldb, BsW + 4096);
        __syncthreads();

        bf16x8 af[4], bfr[4];
#pragma unroll
        for (int i = 0; i < 4; ++i)
            af[i] = *reinterpret_cast<const bf16x8*>(&As[(wm + i * 16 + fr) * 32 + fq * 8]);
#pragma unroll
        for (int j = 0; j < 4; ++j)
            bfr[j] = *reinterpret_cast<const bf16x8*>(&Bs[(wn + j * 16 + fr) * 32 + fq * 8]);
#pragma unroll
        for (int i = 0; i < 4; ++i)
#pragma unroll
            for (int j = 0; j < 4; ++j)
                acc[i][j] = __builtin_amdgcn_mfma_f32_16x16x32_bf16(af[i], bfr[j], acc[i][j], 0, 0, 0);
        __syncthreads();
    }

#pragma unroll
    for (int j = 0; j < 4; ++j) {
        const int col = n0 + wn + j * 16 + fr;
        float bv;
        if constexpr (EPI == 1) bv = (col < 512) ? bias[col] : bias2[col - 512];
        else                    bv = bias ? bias[col] : 0.f;
#pragma unroll
        for (int i = 0; i < 4; ++i) {
#pragma unroll
            for (int r = 0; r < 4; ++r) {
                const long long row = m0 + wm + i * 16 + fq * 4 + r;
                const float v = acc[i][j][r];
                if constexpr (EPI == 0) {
                    outb[(long long)z * sO + row * N + col] = __float2bfloat16(v * scale + bv);
                } else if constexpr (EPI == 1) {
                    if (col < 512) outb[row * 512 + col] = __float2bfloat16(v + bv);
                    else           outb2[row * 512 + (col - 512)] = __float2bfloat16(v + bv);
                } else {
                    const float pd = v + bv;
                    const float pa = pd + anchor[(row >> 11) * 512 + col];
                    nt_store1(&out1[row * N + col], pd);
                    nt_store1(&out2[row * N + col], pa);
                    outb[row * N + col] = __float2bfloat16(pa);
                }
            }
        }
    }
}

// ---------------------------------------------------------------------------
// standalone PV GEMM (batch-pinned)
// ---------------------------------------------------------------------------
__global__ __launch_bounds__(256)
void k_pv(const bf16* __restrict__ Pb, const bf16* __restrict__ Vt,
          bf16* __restrict__ ctx)
{
    __shared__ short SH[8192];
    mfma_core<0, 0>(blockIdx.x, 512, SH, SH + 4096,
                    Pb, 4194304LL, 2048, Vt, 1048576LL, 2048,
                    nullptr, nullptr, ctx, nullptr, 1048576LL,
                    nullptr, nullptr, nullptr, 512, 2048, 1.f, 4);
}

// ---------------------------------------------------------------------------
// merged q-projection + KV-projection (independent GEMMs, one launch).
// blocks 0..511: q = query_b @ wtq^T -> S2;  512..1535: KV dual -> S3, v_b.
// ---------------------------------------------------------------------------
__global__ __launch_bounds__(256)
void k_proj(const bf16* __restrict__ S0q, const bf16* __restrict__ wtq,
            const float* __restrict__ bq, bf16* __restrict__ S2,
            const bf16* __restrict__ S1, const bf16* __restrict__ wtk,
            const float* __restrict__ bk, const float* __restrict__ bv,
            bf16* __restrict__ S3, bf16* __restrict__ v_b)
{
    __shared__ short SH[8192];
    const int b = blockIdx.x;
    if (b < 512) {
        mfma_core<0, 1>(b, 512, SH, SH + 4096,
                        S0q, 0, 512, wtq, 0, 512, bq, nullptr,
                        S2, nullptr, 0, nullptr, nullptr, nullptr,
                        512, 512, 1.f, 4);
    } else {
        mfma_core<1, 1>(b - 512, 1024, SH, SH + 4096,
                        S1, 0, 512, wtk, 0, 512, bk, bv,
                        S3, v_b, 0, nullptr, nullptr, nullptr,
                        1024, 512, 1.f, 8);
    }
}

// ---------------------------------------------------------------------------
// merged V-transpose + QK^T (independent, one launch).
// blocks 0..8191: transpose v_b [B*2048][512] -> S4 [B][512][2048].
// blocks 8192..10239: QK^T (batch-pinned) -> bf16 p_b.
// ---------------------------------------------------------------------------
__global__ __launch_bounds__(256)
void k_qkt_trb(const bf16* __restrict__ v_b, bf16* __restrict__ vt,
               const bf16* __restrict__ S2q, const bf16* __restrict__ S3k,
               bf16* __restrict__ p_b, float scale)
{
    __shared__ short SH[8192];
    const int b = blockIdx.x;
    if (b < 8192) {
        u16 (*t)[36] = (u16(*)[36])SH;
        const int z = b >> 10;
        const int bi = b & 1023;
        const int h0 = (bi & 15) * 32, s0 = (bi >> 4) * 32;
        const int tr = threadIdx.x >> 3, tc = (threadIdx.x & 7) * 4;
        u16x4v a = *reinterpret_cast<const u16x4v*>(
            v_b + ((long long)z * 2048 + s0 + tr) * 512 + h0 + tc);
        t[tr][tc] = a[0]; t[tr][tc + 1] = a[1]; t[tr][tc + 2] = a[2]; t[tr][tc + 3] = a[3];
        __syncthreads();
        u16x4v o;
        o[0] = t[tc + 0][tr]; o[1] = t[tc + 1][tr]; o[2] = t[tc + 2][tr]; o[3] = t[tc + 3][tr];
        *reinterpret_cast<u16x4v*>(
            vt + (long long)z * 1048576 + (long long)(h0 + tr) * 2048 + s0 + tc) = o;
    } else {
        mfma_core<0, 0>(b - 8192, 2048, SH, SH + 4096,
                        S2q, 2048LL * 512, 512, S3k, 2048LL * 512, 512,
                        nullptr, nullptr, p_b, nullptr, 4194304LL,
                        nullptr, nullptr, nullptr, 2048, 512, scale, 16);
    }
}

// ---------------------------------------------------------------------------
// merged local/style f32->bf16 convert + Wo projection (independent).
// blocks 0..8191: cvt;  8192..8703: Wo GEMM + prior epilogue (nt pd/pa).
// ---------------------------------------------------------------------------
__global__ __launch_bounds__(256)
void k_wo_cvt(const float* __restrict__ local_, bf16* __restrict__ S3d,
              const float* __restrict__ style, bf16* __restrict__ S4d,
              const bf16* __restrict__ S1ctx, const bf16* __restrict__ wto,
              const float* __restrict__ bo, bf16* __restrict__ S2pa,
              float* __restrict__ o_pd, float* __restrict__ o_pa,
              const float* __restrict__ anchor)
{
    __shared__ short SH[8192];
    const int b = blockIdx.x;
    if (b < 8192) {
        const float* s = (b < 4096) ? local_ : style;
        bf16* d = (b < 4096) ? S3d : S4d;
        const long long i = ((long long)(b & 4095) * 256 + threadIdx.x) * 8;
        float x[8]; load8f(s + i, x);
        u16x8 o;
#pragma unroll
        for (int j = 0; j < 8; ++j) o[j] = f2u(x[j]);
        *reinterpret_cast<u16x8*>(d + i) = o;
    } else {
        mfma_core<2, 1>(b - 8192, 512, SH, SH + 4096,
                        S1ctx, 0, 512, wto, 0, 512, bo, nullptr,
                        S2pa, nullptr, 0, o_pd, o_pa, anchor,
                        512, 512, 1.f, 4);
    }
}

// ---------------------------------------------------------------------------
// Softmax over bf16 logit rows of 2048 (one block/row): writes f32 attn (nt)
// and normalized bf16 P in-place.
// ---------------------------------------------------------------------------
__global__ __launch_bounds__(256)
void k_softmax_b(bf16* __restrict__ Lb, float* __restrict__ attn)
{
    __shared__ float redm[4], reds[4];
    const long long row = blockIdx.x;
    bf16* lp = Lb + row * 2048;
    float* ap = attn + row * 2048;
    const int tid = threadIdx.x;

    u16x8 u = *reinterpret_cast<const u16x8*>(lp + tid * 8);
    float x[8];
    float mx = -1e30f;
#pragma unroll
    for (int j = 0; j < 8; ++j) { x[j] = b2f(u[j]); mx = fmaxf(mx, x[j]); }
#pragma unroll
    for (int off = 32; off; off >>= 1) mx = fmaxf(mx, __shfl_xor(mx, off));
    if ((tid & 63) == 0) redm[tid >> 6] = mx;
    __syncthreads();
    mx = fmaxf(fmaxf(redm[0], redm[1]), fmaxf(redm[2], redm[3]));

    float s = 0.f;
#pragma unroll
    for (int j = 0; j < 8; ++j) { x[j] = __expf(x[j] - mx); s += x[j]; }
#pragma unroll
    for (int off = 32; off; off >>= 1) s += __shfl_xor(s, off);
    if ((tid & 63) == 0) reds[tid >> 6] = s;
    __syncthreads();
    const float inv = 1.f / (reds[0] + reds[1] + reds[2] + reds[3]);

    u16x8 ob;
#pragma unroll
    for (int j = 0; j < 8; ++j) { x[j] *= inv; ob[j] = f2u(x[j]); }
    nt_store4(ap + tid * 8,     x[0], x[1], x[2], x[3]);
    nt_store4(ap + tid * 8 + 4, x[4], x[5], x[6], x[7]);
    *reinterpret_cast<u16x8*>(lp + tid * 8) = ob;
}

// ---------------------------------------------------------------------------
// Concat-gather MFMA GEMM + fused hidden GEMV partial (gate MLPs).
// ---------------------------------------------------------------------------
__global__ __launch_bounds__(256)
void k_cat(const bf16* __restrict__ s0b, const bf16* __restrict__ s1b,
           const bf16* __restrict__ s2b, const bf16* __restrict__ s3b,
           int mode2,
           const bf16* __restrict__ Bt, const float* __restrict__ bias,
           const float* __restrict__ w2, float* __restrict__ part)
{
    __shared__ short As[4096];
    __shared__ short Bs[4096];
    __shared__ float pl[128][2];
    const int tid = threadIdx.x;
    const int lin = blockIdx.x;
    const int q = (int)gridDim.x >> 3;
    const int wq = (lin & 7) * q + (lin >> 3);
    const int xt = wq & 3;
    const int n0 = xt * 128, m0 = (wq >> 2) * 128;
    const int lrow = tid >> 2;
    const int lcol = (tid & 3) * 8;
    const int lane = tid & 63, w = tid >> 6;
    const int wm = (w >> 1) * 64, wn = (w & 1) * 64;
    const int fr = lane & 15, fq = lane >> 4;
    char* AsW = (char*)As + w * 1024;
    char* BsW = (char*)Bs + w * 1024;

    f32x4 acc[4][4];
#pragma unroll
    for (int i = 0; i < 4; ++i)
#pragma unroll
        for (int j = 0; j < 4; ++j) acc[i][j] = f32x4{0.f, 0.f, 0.f, 0.f};

    for (int k0 = 0; k0 < 2048; k0 += 32) {
        const int si = k0 >> 9;
        const bf16* sp = si == 0 ? s0b : si == 1 ? s1b : si == 2 ? s2b : s3b;
        const int kloc = (k0 & 511) + lcol;
        const int r = m0 + lrow;
        long long ro0, ro1;
        if (si == 2 && mode2) { ro0 = (long long)(r >> 11) * 512; ro1 = ro0; }
        else                  { ro0 = (long long)r * 512; ro1 = ro0 + 64LL * 512; }
        gld16(sp + ro0 + kloc, AsW);
        gld16(sp + ro1 + kloc, AsW + 4096);
        const bf16* gb = Bt + (long long)(n0 + lrow) * 2048 + (k0 + lcol);
        gld16(gb, BsW);
        gld16(gb + 64LL * 2048, BsW + 4096);
        __syncthreads();

        bf16x8 af[4], bfr[4];
#pragma unroll
        for (int i = 0; i < 4; ++i)
            af[i] = *reinterpret_cast<const bf16x8*>(&As[(wm + i * 16 + fr) * 32 + fq * 8]);
#pragma unroll
        for (int j = 0; j < 4; ++j)
            bfr[j] = *reinterpret_cast<const bf16x8*>(&Bs[(wn + j * 16 + fr) * 32 + fq * 8]);
#pragma unroll
        for (int i = 0; i < 4; ++i)
#pragma unroll
            for (int j = 0; j < 4; ++j)
                acc[i][j] = __builtin_amdgcn_mfma_f32_16x16x32_bf16(af[i], bfr[j], acc[i][j], 0, 0, 0);
        __syncthreads();
    }

    float pt[4][4];
#pragma unroll
    for (int i = 0; i < 4; ++i)
#pragma unroll
        for (int r = 0; r < 4; ++r) pt[i][r] = 0.f;
#pragma unroll
    for (int j = 0; j < 4; ++j) {
        const int col = n0 + wn + j * 16 + fr;
        const float bv = bias[col];
        const float wv = w2[col];
#pragma unroll
        for (int i = 0; i < 4; ++i)
#pragma unroll
            for (int r = 0; r < 4; ++r)
                pt[i][r] = fmaf(fmaxf(acc[i][j][r] + bv, 0.f), wv, pt[i][r]);
    }
#pragma unroll
    for (int off = 1; off < 16; off <<= 1)
#pragma unroll
        for (int i = 0; i < 4; ++i)
#pragma unroll
            for (int r = 0; r < 4; ++r)
                pt[i][r] += __shfl_xor(pt[i][r], off);
    if (fr == 0)
#pragma unroll
        for (int i = 0; i < 4; ++i)
#pragma unroll
            for (int r = 0; r < 4; ++r)
                pl[wm + i * 16 + fq * 4 + r][wn >> 6] = pt[i][r];
    __syncthreads();
    if (tid < 128)
        part[(long long)(m0 + tid) * 4 + xt] = pl[tid][0] + pl[tid][1];
}

// ---------------------------------------------------------------------------
// Fat prologue: query/gmem/anchor f32->bf16 + 6 weight transposes.
// ---------------------------------------------------------------------------
__global__ __launch_bounds__(256)
void k_prologue(const float* __restrict__ query, bf16* __restrict__ qb,
                const float* __restrict__ gmem, bf16* __restrict__ gb,
                const float* __restrict__ anchor, bf16* __restrict__ anb,
                const float* Wq, bf16* wtq, const float* Wk, bf16* wtk,
                const float* Wv, bf16* wtv, const float* Wo, bf16* wto,
                const float* Wm1, bf16* wtm1, const float* Wg1, bf16* wtg1)
{
    __shared__ float tls[32][33];
    const int b = blockIdx.x;
    const int tid = threadIdx.x;
    if (b < 8192) {
        const float* s = (b < 4096) ? query : gmem;
        bf16* d = (b < 4096) ? qb : gb;
        const long long i = ((long long)(b & 4095) * 256 + tid) * 8;
        float x[8]; load8f(s + i, x);
        u16x8 o;
#pragma unroll
        for (int j = 0; j < 8; ++j) o[j] = f2u(x[j]);
        *reinterpret_cast<u16x8*>(d + i) = o;
        return;
    }
    if (b < 8194) {
        const int i = ((b - 8192) * 256 + tid) * 8;
        if (i < 4096) {
            float x[8]; load8f(anchor + i, x);
            u16x8 o;
#pragma unroll
            for (int j = 0; j < 8; ++j) o[j] = f2u(x[j]);
            *reinterpret_cast<u16x8*>(anb + i) = o;
        }
        return;
    }
    const float* s; bf16* d; int R, C, ti;
    if (b < 9218) {
        const int bi = b - 8194; const int zz = bi >> 8; ti = bi & 255;
        s = zz == 0 ? Wq : zz == 1 ? Wk : zz == 2 ? Wv : Wo;
        d = zz == 0 ? wtq : zz == 1 ? wtk : zz == 2 ? wtv : wto;
        R = 512; C = 512;
    } else {
        const int bi = b - 9218; const int zz = bi >> 10; ti = bi & 1023;
        s = zz ? Wg1 : Wm1; d = zz ? wtg1 : wtm1;
        R = 2048; C = 512;
    }
    const int c0 = (ti & 15) * 32, r0 = (ti >> 4) * 32;
    const int tr = tid >> 3, tc = (tid & 7) * 4;
    float4 v = *reinterpret_cast<const float4*>(s + (long long)(r0 + tr) * C + c0 + tc);
    tls[tr][tc] = v.x; tls[tr][tc + 1] = v.y; tls[tr][tc + 2] = v.z; tls[tr][tc + 3] = v.w;
    __syncthreads();
    u16x4v o;
    o[0] = f2u(tls[tc + 0][tr]); o[1] = f2u(tls[tc + 1][tr]);
    o[2] = f2u(tls[tc + 2][tr]); o[3] = f2u(tls[tc + 3][tr]);
    *reinterpret_cast<u16x4v*>(d + (long long)(c0 + tr) * R + r0 + tc) = o;
}

// ---------------------------------------------------------------------------
// mix finisher + slerp, one wave per row (nt on f32 cand/cdelta).
// ---------------------------------------------------------------------------
__global__ __launch_bounds__(64)
void k_gate_slerp(const float* __restrict__ part, const float* __restrict__ b2,
                  const bf16* __restrict__ priorb, const bf16* __restrict__ localb,
                  const float* __restrict__ anchor,
                  float* __restrict__ o_mix,
                  float* __restrict__ cand, float* __restrict__ cdelta,
                  bf16* __restrict__ candb)
{
    const int row = blockIdx.x;
    const int lane = threadIdx.x;
    float v = (lane < 4) ? part[(long long)row * 4 + lane] : 0.f;
    v += __shfl_xor(v, 1);
    v += __shfl_xor(v, 2);
    const float logit = __shfl(v, 0) + b2[0];
    float t = sigmoidf_(logit - 0.25f);
    if (lane == 0) o_mix[row] = t;
    t = fminf(fmaxf(t, 0.f), 1.f);

    const long long base = (long long)row * 512 + lane * 8;
    const long long abase = (long long)(row >> 11) * 512 + lane * 8;
    u16x8 ua = *reinterpret_cast<const u16x8*>(priorb + base);
    u16x8 ub = *reinterpret_cast<const u16x8*>(localb + base);
    float a[8], b[8];
    float sa = 0.f, sb = 0.f, sab = 0.f;
#pragma unroll
    for (int j = 0; j < 8; ++j) {
        a[j] = b2f(ua[j]); b[j] = b2f(ub[j]);
        sa = fmaf(a[j], a[j], sa); sb = fmaf(b[j], b[j], sb); sab = fmaf(a[j], b[j], sab);
    }
#pragma unroll
    for (int off = 1; off < 64; off <<= 1) {
        sa += __shfl_xor(sa, off); sb += __shfl_xor(sb, off); sab += __shfl_xor(sab, off);
    }
    const float eps = 1e-6f;
    float na = fmaxf(sqrtf(sa), eps), nb = fmaxf(sqrtf(sb), eps);
    float dot = sab / (na * nb);
    dot = fminf(fmaxf(dot, -1.f + eps), 1.f - eps);
    float omega = acosf(dot);
    float so = fmaxf(sinf(omega), eps);
    float sca = sinf((1.f - t) * omega) / so;
    float scb = sinf(t * omega) / so;

    float an[8];
    load8f(anchor + abase, an);
    float c0[8], d0[8];
    u16x8 cb;
#pragma unroll
    for (int j = 0; j < 8; ++j) {
        c0[j] = sca * a[j] + scb * b[j];
        d0[j] = c0[j] - an[j];
        cb[j] = f2u(c0[j]);
    }
    nt_store4(cand + base,       c0[0], c0[1], c0[2], c0[3]);
    nt_store4(cand + base + 4,   c0[4], c0[5], c0[6], c0[7]);
    nt_store4(cdelta + base,     d0[0], d0[1], d0[2], d0[3]);
    nt_store4(cdelta + base + 4, d0[4], d0[5], d0[6], d0[7]);
    *reinterpret_cast<u16x8*>(candb + base) = cb;
}

// ---------------------------------------------------------------------------
// variation finisher: thread per row.
// ---------------------------------------------------------------------------
__global__ __launch_bounds__(256)
void k_gate_var(const float* __restrict__ part, const float* __restrict__ b2,
                float* __restrict__ o_vl, float* __restrict__ o_vg)
{
    const long long row = (long long)blockIdx.x * 256 + threadIdx.x;
    float4 p = *reinterpret_cast<const float4*>(part + row * 4);
    const float logit = (p.x + p.y) + (p.z + p.w) + b2[0];
    o_vl[row] = logit;
    o_vg[row] = sigmoidf_(logit - 1.0f);
}

// ---------------------------------------------------------------------------
extern "C" void kernel_launch(void* const* d_in, const int* in_sizes, int n_in,
                              void* d_out, int out_size, void* d_ws, size_t ws_size,
                              hipStream_t stream)
{
    const float* query  = (const float*)d_in[0];
    const float* anchor = (const float*)d_in[1];
    const float* gmem   = (const float*)d_in[2];
    const float* local_ = (const float*)d_in[3];
    const float* style  = (const float*)d_in[4];
    const float* Wq = (const float*)d_in[5];   const float* bq = (const float*)d_in[6];
    const float* Wk = (const float*)d_in[7];   const float* bk = (const float*)d_in[8];
    const float* Wv = (const float*)d_in[9];   const float* bv = (const float*)d_in[10];
    const float* Wo = (const float*)d_in[11];  const float* bo = (const float*)d_in[12];
    const float* Wm1 = (const float*)d_in[13]; const float* bm1 = (const float*)d_in[14];
    const float* Wm2 = (const float*)d_in[15]; const float* bm2 = (const float*)d_in[16];
    const float* Wg1 = (const float*)d_in[17]; const float* bg1 = (const float*)d_in[18];
    const float* Wg2 = (const float*)d_in[19]; const float* bg2 = (const float*)d_in[20];

    float* out = (float*)d_out;
    const long long SHE = 8388608LL;             // B*S*H elems
    float* o_attn = out;                         // [B,S,M]
    float* o_pd   = out + 33554432LL;            // prior_delta
    float* o_pa   = o_pd + SHE;                  // prior_absolute
    float* o_mix  = o_pa + SHE;                  // mix [16384]
    float* o_ca   = o_mix + 16384;               // candidate_absolute
    float* o_cd   = o_ca + SHE;                  // candidate_delta
    float* o_vl   = o_cd + SHE;                  // variation_logit
    float* o_vg   = o_vl + 16384;                // variation_gate

    // ws slots (bf16, 8.4M elems each, aggressively reused):
    bf16* S0q = (bf16*)d_ws;       // query_b (whole run)
    bf16* S1  = S0q + SHE;         // gmem_b -> ctx_b
    bf16* S2  = S1 + SHE;          // q_b -> pa_b -> ca_b
    bf16* S3  = S2 + SHE;          // k_b -> local_b
    bf16* S4  = S3 + SHE;          // v_t -> style_b
    bf16* wtq = S4 + SHE;          // transposed weights (bf16)
    bf16* wtk = wtq + 262144;      // wtk,wtv contiguous => KV merged B [1024][512]
    bf16* wtv = wtk + 262144;
    bf16* wto = wtv + 262144;
    bf16* wtm1 = wto + 262144;     // [512][2048]
    bf16* wtg1 = wtm1 + 1048576;   // [512][2048]
    bf16* anb  = wtg1 + 1048576;   // anchor_b [8,512]
    float* part_m = (float*)(anb + 4096);  // [16384][4]
    float* part_v = part_m + 65536;        // [16384][4]
    bf16* p_b  = (bf16*)o_ca;      // bf16 logits->P in d_out o_ca+o_cd (67 MB)
    bf16* v_b  = (bf16*)o_attn;    // row-major v staging in o_attn (dead until softmax)

    const float invSqrtH = 0.04419417382415922f; // 1/sqrt(512)

    // fat prologue: all conversions + weight transposes
    k_prologue<<<11266, 256, 0, stream>>>(query, S0q, gmem, S1, anchor, anb,
        Wq, wtq, Wk, wtk, Wv, wtv, Wo, wto, Wm1, wtm1, Wg1, wtg1);
    // merged q-projection + KV-projection
    k_proj<<<1536, 256, 0, stream>>>(S0q, wtq, bq, S2, S1, wtk, bk, bv, S3, v_b);
    // merged V-transpose (v_b -> S4) + QK^T (q.k^T -> p_b)
    k_qkt_trb<<<10240, 256, 0, stream>>>(v_b, S4, S2, S3, p_b, invSqrtH);
    // softmax: bf16 logits -> f32 attn (nt) + normalized bf16 P in place
    k_softmax_b<<<16384, 256, 0, stream>>>(p_b, o_attn);
    // PV (batch-pinned): P_b . v_t^T -> ctx_b (S1)
    k_pv<<<512, 256, 0, stream>>>(p_b, S4, S1);
    // merged local/style cvt (-> S3,S4) + Wo projection (pd/pa nt, pa_b -> S2)
    k_wo_cvt<<<8704, 256, 0, stream>>>(local_, S3, style, S4, S1, wto, bo,
        S2, o_pd, o_pa, anchor);
    // mix gate MLP -> per-block partials
    k_cat<<<512, 256, 0, stream>>>(S0q, S2, S3, S4, 0, wtm1, bm1, Wm2, part_m);
    // mix finisher + slerp (reads pa_b, writes ca/cd nt + ca_b in place)
    k_gate_slerp<<<16384, 64, 0, stream>>>(part_m, bm2, S2, S3, anchor,
        o_mix, o_ca, o_cd, S2);
    // variation gate MLP (src2 = anchor_b broadcast)
    k_cat<<<512, 256, 0, stream>>>(S0q, S2, anb, S4, 1, wtg1, bg1, Wg2, part_v);
    k_gate_var<<<64, 256, 0, stream>>>(part_v, bg2, o_vl, o_vg);
}